// Round 1
// baseline (1929.793 us; speedup 1.0000x reference)
//
#include <hip/hip_runtime.h>
#include <math.h>

#define NN 4096
#define NE 131072

__device__ __forceinline__ unsigned fkey(float f) {
  unsigned u = __float_as_uint(f);
  return (u & 0x80000000u) ? ~u : (u | 0x80000000u);
}
__device__ __forceinline__ float fdec(unsigned k) {
  unsigned u = (k & 0x80000000u) ? (k ^ 0x80000000u) : ~k;
  return __uint_as_float(u);
}

// ---------------- gather + concat embeddings ----------------
__global__ void k_gather(const int* __restrict__ node_x, const float* __restrict__ uw,
                         const float* __restrict__ iw, float* __restrict__ x0) {
  int n = blockIdx.x, t = threadIdx.x;  // 128 threads
  int u = node_x[n * 2], it = node_x[n * 2 + 1];
  x0[n * 128 + t] = (t < 64) ? uw[u * 64 + t] : iw[it * 64 + (t - 64)];
}

// ---------------- generic fp32 GEMM: C = A(MxK) @ B(KxN) [+bias][+=C][relu] ----------------
// flags: bit0 = relu, bit1 = accumulate into existing C
__global__ __launch_bounds__(256) void k_gemm(const float* __restrict__ A, const float* __restrict__ B,
                                              const float* __restrict__ bias, float* __restrict__ C,
                                              int M, int N, int K, int flags) {
  __shared__ float As[16][65];
  __shared__ float Bs[16][65];
  int bm = blockIdx.y * 64;
  int bn = blockIdx.x * 64;
  int tid = threadIdx.x;
  int tx = tid & 15, ty = tid >> 4;
  float acc[4][4] = {};
  for (int k0 = 0; k0 < K; k0 += 16) {
    // A tile: 64 rows x 16 k, float4 per thread (M, K are multiples of 64/16 here)
    {
      int row = tid >> 2;
      int kk = (tid & 3) * 4;
      const float4 av = *reinterpret_cast<const float4*>(A + (size_t)(bm + row) * K + k0 + kk);
      As[kk + 0][row] = av.x; As[kk + 1][row] = av.y; As[kk + 2][row] = av.z; As[kk + 3][row] = av.w;
    }
    // B tile: 16 rows x 64 cols, guarded on N
    {
      int col = tid & 63;
      int rb = tid >> 6;
      int gc = bn + col;
#pragma unroll
      for (int r = 0; r < 4; r++) {
        int row = rb + r * 4;
        Bs[row][col] = (gc < N) ? B[(size_t)(k0 + row) * N + gc] : 0.f;
      }
    }
    __syncthreads();
#pragma unroll
    for (int k = 0; k < 16; k++) {
      float a[4], b[4];
#pragma unroll
      for (int i = 0; i < 4; i++) a[i] = As[k][ty * 4 + i];
#pragma unroll
      for (int j = 0; j < 4; j++) b[j] = Bs[k][tx * 4 + j];
#pragma unroll
      for (int i = 0; i < 4; i++)
#pragma unroll
        for (int j = 0; j < 4; j++) acc[i][j] = fmaf(a[i], b[j], acc[i][j]);
    }
    __syncthreads();
  }
#pragma unroll
  for (int i = 0; i < 4; i++) {
    int gr = bm + ty * 4 + i;
#pragma unroll
    for (int j = 0; j < 4; j++) {
      int gc = bn + tx * 4 + j;
      if (gc < N) {
        float v = acc[i][j];
        if (bias) v += bias[gc];
        size_t o = (size_t)gr * N + gc;
        if (flags & 2) v += C[o];
        if (flags & 1) v = fmaxf(v, 0.f);
        C[o] = v;
      }
    }
  }
}

// ---------------- degree / scatter helpers ----------------
__global__ void k_count(const int* __restrict__ idx, int* __restrict__ deg, int n) {
  for (int i = blockIdx.x * blockDim.x + threadIdx.x; i < n; i += gridDim.x * blockDim.x)
    atomicAdd(&deg[idx[i]], 1);
}

__global__ void k_dinv(const int* __restrict__ deg, float* __restrict__ dinv, int n, int self) {
  int i = blockIdx.x * blockDim.x + threadIdx.x;
  if (i < n) {
    int d = deg[i] + self;
    dinv[i] = d > 0 ? rsqrtf((float)d) : 0.f;
  }
}

// agg[v][f] = h[v][f] * dinv[v]^2   (GCN self-loop term, also inits agg)
__global__ void k_gcn_self(const float* __restrict__ h, const float* __restrict__ dinv,
                           float* __restrict__ agg, int logF, int n) {
  for (int i = blockIdx.x * blockDim.x + threadIdx.x; i < n; i += gridDim.x * blockDim.x) {
    float d = dinv[i >> logF];
    agg[i] = h[i] * d * d;
  }
}

__global__ void k_gcn_scatter(const float* __restrict__ h, const int* __restrict__ ei0,
                              const int* __restrict__ ei1, const float* __restrict__ dinv,
                              float* __restrict__ agg, int logF, int n) {
  int F1 = (1 << logF) - 1;
  for (int i = blockIdx.x * blockDim.x + threadIdx.x; i < n; i += gridDim.x * blockDim.x) {
    int e = i >> logF, f = i & F1;
    int r = ei0[e], c = ei1[e];
    atomicAdd(&agg[((size_t)c << logF) + f], h[((size_t)r << logF) + f] * dinv[r] * dinv[c]);
  }
}

__global__ void k_scatter_plain(const float* __restrict__ x, const int* __restrict__ ei0,
                                const int* __restrict__ ei1, float* __restrict__ agg, int n) {
  for (int i = blockIdx.x * blockDim.x + threadIdx.x; i < n; i += gridDim.x * blockDim.x) {
    int e = i >> 7, f = i & 127;
    int r = ei0[e], c = ei1[e];
    atomicAdd(&agg[((size_t)c << 7) + f], x[((size_t)r << 7) + f]);
  }
}

__global__ void k_scatter_cheb(const float* __restrict__ x, const int* __restrict__ ei0,
                               const int* __restrict__ ei1, const float* __restrict__ dinv,
                               float* __restrict__ agg, int n) {
  for (int i = blockIdx.x * blockDim.x + threadIdx.x; i < n; i += gridDim.x * blockDim.x) {
    int e = i >> 7, f = i & 127;
    int r = ei0[e], c = ei1[e];
    float w = -(dinv[r] * dinv[c]);
    atomicAdd(&agg[((size_t)c << 7) + f], x[((size_t)r << 7) + f] * w);
  }
}

__global__ void k_sage_div(float* __restrict__ agg, const int* __restrict__ cnt, int n) {
  for (int i = blockIdx.x * blockDim.x + threadIdx.x; i < n; i += gridDim.x * blockDim.x) {
    float c = (float)cnt[i >> 7];
    agg[i] = agg[i] / fmaxf(c, 1.f);
  }
}

// ---------------- batch norm ----------------
__global__ void k_bn_stats(const float* __restrict__ x, float* __restrict__ sum,
                           float* __restrict__ sumsq, int F) {
  // grid = NN/64 blocks of 256; F divides 256
  int tid = threadIdx.x;
  int f = tid & (F - 1);
  int rstep = 256 / F;
  int r0 = tid / F;
  int base = blockIdx.x * 64;
  float s = 0.f, s2 = 0.f;
  for (int rr = r0; rr < 64; rr += rstep) {
    float v = x[(size_t)(base + rr) * F + f];
    s += v;
    s2 += v * v;
  }
  atomicAdd(&sum[f], s);
  atomicAdd(&sumsq[f], s2);
}

__global__ void k_bn_final(const float* __restrict__ sum, const float* __restrict__ sumsq,
                           const float* __restrict__ g, const float* __restrict__ be,
                           float* __restrict__ scale, float* __restrict__ shift, int F) {
  int f = blockIdx.x * blockDim.x + threadIdx.x;
  if (f < F) {
    float invM = 1.f / (float)NN;
    float mu = sum[f] * invM;
    float var = sumsq[f] * invM - mu * mu;
    float sc = g[f] * rsqrtf(var + 1e-5f);
    scale[f] = sc;
    shift[f] = be[f] - mu * sc;
  }
}

__global__ void k_bn_apply_relu(const float* __restrict__ x, const float* __restrict__ scale,
                                const float* __restrict__ shift, float* __restrict__ y,
                                int logF, int n) {
  int F1 = (1 << logF) - 1;
  for (int i = blockIdx.x * blockDim.x + threadIdx.x; i < n; i += gridDim.x * blockDim.x) {
    int f = i & F1;
    y[i] = fmaxf(x[i] * scale[f] + shift[f], 0.f);
  }
}

// ---------------- GAT ----------------
__global__ void k_gat_dots(const float* __restrict__ h, const float* __restrict__ asrc,
                           const float* __restrict__ adst, float* __restrict__ a_s,
                           float* __restrict__ a_d) {
  int n = blockIdx.x, l = threadIdx.x;  // 64 threads
  float h0 = h[n * 128 + l], h1 = h[n * 128 + 64 + l];
  float hs = h0 * asrc[l] + h1 * asrc[64 + l];
  float hd = h0 * adst[l] + h1 * adst[64 + l];
  for (int off = 32; off; off >>= 1) {
    hs += __shfl_down(hs, off, 64);
    hd += __shfl_down(hd, off, 64);
  }
  if (l == 0) {
    a_s[n] = hs;
    a_d[n] = hd;
  }
}

__global__ void k_gat_e(const int* __restrict__ ei0, const int* __restrict__ ei1,
                        const float* __restrict__ a_s, const float* __restrict__ a_d,
                        float* __restrict__ ee, unsigned* __restrict__ emax) {
  for (int e = blockIdx.x * blockDim.x + threadIdx.x; e < NE + NN; e += gridDim.x * blockDim.x) {
    int r, c;
    if (e < NE) { r = ei0[e]; c = ei1[e]; } else { r = c = e - NE; }
    float v = a_s[r] + a_d[c];
    v = v >= 0.f ? v : 0.2f * v;  // leaky_relu 0.2
    ee[e] = v;
    atomicMax(&emax[c], fkey(v));
  }
}

__global__ void k_gat_ex(const int* __restrict__ ei1, const unsigned* __restrict__ emax,
                         float* __restrict__ ee, float* __restrict__ denom) {
  for (int e = blockIdx.x * blockDim.x + threadIdx.x; e < NE + NN; e += gridDim.x * blockDim.x) {
    int c = (e < NE) ? ei1[e] : e - NE;
    float v = expf(ee[e] - fdec(emax[c]));
    ee[e] = v;
    atomicAdd(&denom[c], v);
  }
}

__global__ void k_gat_alpha(const int* __restrict__ ei1, const float* __restrict__ denom,
                            float* __restrict__ ee) {
  for (int e = blockIdx.x * blockDim.x + threadIdx.x; e < NE + NN; e += gridDim.x * blockDim.x) {
    int c = (e < NE) ? ei1[e] : e - NE;
    ee[e] = ee[e] / denom[c];
  }
}

__global__ void k_gat_scatter(const float* __restrict__ h, const int* __restrict__ ei0,
                              const int* __restrict__ ei1, const float* __restrict__ ee,
                              float* __restrict__ agg, int n) {
  for (int i = blockIdx.x * blockDim.x + threadIdx.x; i < n; i += gridDim.x * blockDim.x) {
    int e = i >> 7, f = i & 127;
    int r, c;
    if (e < NE) { r = ei0[e]; c = ei1[e]; } else { r = c = e - NE; }
    atomicAdd(&agg[((size_t)c << 7) + f], h[((size_t)r << 7) + f] * ee[e]);
  }
}

__global__ void k_elu_bias(const float* __restrict__ agg, const float* __restrict__ b,
                           float* __restrict__ out, int n) {
  for (int i = blockIdx.x * blockDim.x + threadIdx.x; i < n; i += gridDim.x * blockDim.x) {
    float v = agg[i] + b[i & 127];
    out[i] = v > 0.f ? v : expm1f(v);
  }
}

// ---------------- launch ----------------
static inline int cdiv(int a, int b) { return (a + b - 1) / b; }

extern "C" void kernel_launch(void* const* d_in, const int* in_sizes, int n_in,
                              void* d_out, int out_size, void* d_ws, size_t ws_size,
                              hipStream_t stream) {
  const int* ei0 = (const int*)d_in[0];
  const int* ei1 = ei0 + NE;
  const int* node_x = (const int*)d_in[1];
  const float* user_w = (const float*)d_in[2];
  const float* item_w = (const float*)d_in[3];
  const float* mlp_w1 = (const float*)d_in[4];
  const float* mlp_b1 = (const float*)d_in[5];
  const float* mlp_w2 = (const float*)d_in[6];
  const float* mlp_b2 = (const float*)d_in[7];
  const float* gcn_w1 = (const float*)d_in[8];
  // d_in[9] gcn_b1: mathematically cancelled by batch_norm mean subtraction
  const float* bn1_g = (const float*)d_in[10];
  const float* bn1_b = (const float*)d_in[11];
  const float* gcn_w2 = (const float*)d_in[12];
  // d_in[13] gcn_b2: cancelled by BN
  const float* bn2_g = (const float*)d_in[14];
  const float* bn2_b = (const float*)d_in[15];
  const float* sage_wl = (const float*)d_in[16];
  const float* sage_bl = (const float*)d_in[17];
  const float* sage_wr = (const float*)d_in[18];
  const float* cheb_w0 = (const float*)d_in[19];
  const float* cheb_w1 = (const float*)d_in[20];
  const float* cheb_b = (const float*)d_in[21];
  const float* gat1_w = (const float*)d_in[22];
  const float* gat1_as = (const float*)d_in[23];
  const float* gat1_ad = (const float*)d_in[24];
  const float* gat1_b = (const float*)d_in[25];
  const float* gat2_w = (const float*)d_in[26];
  const float* gat2_as = (const float*)d_in[27];
  const float* gat2_ad = (const float*)d_in[28];
  const float* gat2_b = (const float*)d_in[29];
  const float* pred_w = (const float*)d_in[30];
  const float* pred_b = (const float*)d_in[31];

  // ---- workspace layout (~27 MB) ----
  char* w = (char*)d_ws;
  size_t off = 0;
  auto alloc = [&](size_t bytes) -> char* {
    char* p = w + off;
    off = (off + bytes + 255) & ~(size_t)255;
    return p;
  };
  float* r1 = (float*)alloc((size_t)NN * 1024 * 4);  // x1, later h/agg/xa/xb
  float* x2 = (float*)alloc((size_t)NN * 512 * 4);
  float* x0 = (float*)alloc((size_t)NN * 128 * 4);
  float* ee = (float*)alloc((size_t)(NE + NN) * 4);
  int* deg = (int*)alloc(NN * 4);
  float* dinvA = (float*)alloc(NN * 4);
  float* dinvB = (float*)alloc(NN * 4);
  float* a_s = (float*)alloc(NN * 4);
  float* a_d = (float*)alloc(NN * 4);
  unsigned* emax = (unsigned*)alloc(NN * 4);
  float* denom = (float*)alloc(NN * 4);
  float* bsum = (float*)alloc(256 * 4);
  float* bsq = (float*)alloc(256 * 4);
  float* bscale = (float*)alloc(256 * 4);
  float* bshift = (float*)alloc(256 * 4);

  float* h = r1;                 // 4096x256 max
  float* agg = r1 + NN * 256;
  float* xa = r1 + 2 * NN * 256;
  float* xb = r1 + 3 * NN * 256;

  const int GSB = 4096;  // grid-stride blocks

  auto gemm = [&](const float* A, const float* B, const float* bias, float* C,
                  int M, int N, int K, int flags) {
    dim3 g(cdiv(N, 64), M / 64), b(256);
    k_gemm<<<g, b, 0, stream>>>(A, B, bias, C, M, N, K, flags);
  };

  // stage 0: gather
  k_gather<<<NN, 128, 0, stream>>>(node_x, user_w, item_w, x0);
  // stage 1-2: MLP
  gemm(x0, mlp_w1, mlp_b1, r1, NN, 1024, 128, 1);   // x1 = relu(...)
  gemm(r1, mlp_w2, mlp_b2, x2, NN, 512, 1024, 1);   // x2 = relu(...)

  // ---- GCN1 (F=512 -> 256) ----
  gemm(x2, gcn_w1, nullptr, h, NN, 256, 512, 0);
  hipMemsetAsync(deg, 0, NN * 4, stream);
  k_count<<<512, 256, 0, stream>>>(ei1, deg, NE);
  k_dinv<<<cdiv(NN, 256), 256, 0, stream>>>(deg, dinvA, NN, 1);  // +1 self loop
  k_gcn_self<<<GSB, 256, 0, stream>>>(h, dinvA, agg, 8, NN * 256);
  k_gcn_scatter<<<GSB, 256, 0, stream>>>(h, ei0, ei1, dinvA, agg, 8, NE * 256);
  hipMemsetAsync(bsum, 0, 256 * 4, stream);
  hipMemsetAsync(bsq, 0, 256 * 4, stream);
  k_bn_stats<<<NN / 64, 256, 0, stream>>>(agg, bsum, bsq, 256);
  k_bn_final<<<1, 256, 0, stream>>>(bsum, bsq, bn1_g, bn1_b, bscale, bshift, 256);
  k_bn_apply_relu<<<GSB, 256, 0, stream>>>(agg, bscale, bshift, xa, 8, NN * 256);

  // ---- GCN2 (256 -> 128) ----
  gemm(xa, gcn_w2, nullptr, h, NN, 128, 256, 0);
  k_gcn_self<<<GSB, 256, 0, stream>>>(h, dinvA, agg, 7, NN * 128);
  k_gcn_scatter<<<GSB, 256, 0, stream>>>(h, ei0, ei1, dinvA, agg, 7, NE * 128);
  hipMemsetAsync(bsum, 0, 256 * 4, stream);
  hipMemsetAsync(bsq, 0, 256 * 4, stream);
  k_bn_stats<<<NN / 64, 256, 0, stream>>>(agg, bsum, bsq, 128);
  k_bn_final<<<1, 128, 0, stream>>>(bsum, bsq, bn2_g, bn2_b, bscale, bshift, 128);
  k_bn_apply_relu<<<GSB, 256, 0, stream>>>(agg, bscale, bshift, xb, 7, NN * 128);

  // ---- SAGE (x = xb) ----
  hipMemsetAsync(deg, 0, NN * 4, stream);
  k_count<<<512, 256, 0, stream>>>(ei1, deg, NE);
  hipMemsetAsync(agg, 0, (size_t)NN * 128 * 4, stream);
  k_scatter_plain<<<GSB, 256, 0, stream>>>(xb, ei0, ei1, agg, NE * 128);
  k_sage_div<<<GSB, 256, 0, stream>>>(agg, deg, NN * 128);
  gemm(agg, sage_wl, sage_bl, xa, NN, 128, 128, 0);
  gemm(xb, sage_wr, nullptr, xa, NN, 128, 128, 2 | 1);  // accum + relu -> xa

  // ---- Cheb (x = xa) ----
  hipMemsetAsync(deg, 0, NN * 4, stream);
  k_count<<<512, 256, 0, stream>>>(ei0, deg, NE);
  k_dinv<<<cdiv(NN, 256), 256, 0, stream>>>(deg, dinvB, NN, 0);
  hipMemsetAsync(agg, 0, (size_t)NN * 128 * 4, stream);
  k_scatter_cheb<<<GSB, 256, 0, stream>>>(xa, ei0, ei1, dinvB, agg, NE * 128);
  gemm(xa, cheb_w0, cheb_b, xb, NN, 128, 128, 0);
  gemm(agg, cheb_w1, nullptr, xb, NN, 128, 128, 2 | 1);  // accum + relu -> xb

  // ---- GAT1 (x = xb -> xa) ----
  gemm(xb, gat1_w, nullptr, h, NN, 128, 128, 0);
  k_gat_dots<<<NN, 64, 0, stream>>>(h, gat1_as, gat1_ad, a_s, a_d);
  hipMemsetAsync(emax, 0, NN * 4, stream);
  k_gat_e<<<512, 256, 0, stream>>>(ei0, ei1, a_s, a_d, ee, emax);
  hipMemsetAsync(denom, 0, NN * 4, stream);
  k_gat_ex<<<512, 256, 0, stream>>>(ei1, emax, ee, denom);
  k_gat_alpha<<<512, 256, 0, stream>>>(ei1, denom, ee);
  hipMemsetAsync(agg, 0, (size_t)NN * 128 * 4, stream);
  k_gat_scatter<<<GSB, 256, 0, stream>>>(h, ei0, ei1, ee, agg, (NE + NN) * 128);
  k_elu_bias<<<GSB, 256, 0, stream>>>(agg, gat1_b, xa, NN * 128);

  // ---- GAT2 (x = xa -> xb) ----
  gemm(xa, gat2_w, nullptr, h, NN, 128, 128, 0);
  k_gat_dots<<<NN, 64, 0, stream>>>(h, gat2_as, gat2_ad, a_s, a_d);
  hipMemsetAsync(emax, 0, NN * 4, stream);
  k_gat_e<<<512, 256, 0, stream>>>(ei0, ei1, a_s, a_d, ee, emax);
  hipMemsetAsync(denom, 0, NN * 4, stream);
  k_gat_ex<<<512, 256, 0, stream>>>(ei1, emax, ee, denom);
  k_gat_alpha<<<512, 256, 0, stream>>>(ei1, denom, ee);
  hipMemsetAsync(agg, 0, (size_t)NN * 128 * 4, stream);
  k_gat_scatter<<<GSB, 256, 0, stream>>>(h, ei0, ei1, ee, agg, (NE + NN) * 128);
  k_elu_bias<<<GSB, 256, 0, stream>>>(agg, gat2_b, xb, NN * 128);

  // ---- final prediction GEMM ----
  gemm(xb, pred_w, pred_b, (float*)d_out, NN, 41476, 128, 0);
}

// Round 2
// 1238.388 us; speedup vs baseline: 1.5583x; 1.5583x over previous
//
#include <hip/hip_runtime.h>
#include <math.h>

#define NN 4096
#define NE 131072
#define NCLS 41476
#define NPAD 41600  // 325 * 128, zero-padded transposed weight rows

typedef __attribute__((ext_vector_type(8))) unsigned short ushort8;
typedef __attribute__((ext_vector_type(8))) __bf16 bf16x8;
typedef __attribute__((ext_vector_type(4))) float f32x4;

__device__ __forceinline__ unsigned fkey(float f) {
  unsigned u = __float_as_uint(f);
  return (u & 0x80000000u) ? ~u : (u | 0x80000000u);
}
__device__ __forceinline__ float fdec(unsigned k) {
  unsigned u = (k & 0x80000000u) ? (k ^ 0x80000000u) : ~k;
  return __uint_as_float(u);
}
__device__ __forceinline__ unsigned short f2bf(float f) {
  unsigned u = __float_as_uint(f);
  unsigned r = u + 0x7fffu + ((u >> 16) & 1u);  // RNE
  return (unsigned short)(r >> 16);
}

// ---------------- gather + concat embeddings ----------------
__global__ void k_gather(const int* __restrict__ node_x, const float* __restrict__ uw,
                         const float* __restrict__ iw, float* __restrict__ x0) {
  int n = blockIdx.x, t = threadIdx.x;  // 128 threads
  int u = node_x[n * 2], it = node_x[n * 2 + 1];
  x0[n * 128 + t] = (t < 64) ? uw[u * 64 + t] : iw[it * 64 + (t - 64)];
}

// ---------------- generic fp32 GEMM (small layers) ----------------
// flags: bit0 = relu, bit1 = accumulate into existing C
__global__ __launch_bounds__(256) void k_gemm(const float* __restrict__ A, const float* __restrict__ B,
                                              const float* __restrict__ bias, float* __restrict__ C,
                                              int M, int N, int K, int flags) {
  __shared__ float As[16][65];
  __shared__ float Bs[16][65];
  int bm = blockIdx.y * 64;
  int bn = blockIdx.x * 64;
  int tid = threadIdx.x;
  int tx = tid & 15, ty = tid >> 4;
  float acc[4][4] = {};
  for (int k0 = 0; k0 < K; k0 += 16) {
    {
      int row = tid >> 2;
      int kk = (tid & 3) * 4;
      const float4 av = *reinterpret_cast<const float4*>(A + (size_t)(bm + row) * K + k0 + kk);
      As[kk + 0][row] = av.x; As[kk + 1][row] = av.y; As[kk + 2][row] = av.z; As[kk + 3][row] = av.w;
    }
    {
      int col = tid & 63;
      int rb = tid >> 6;
      int gc = bn + col;
#pragma unroll
      for (int r = 0; r < 4; r++) {
        int row = rb + r * 4;
        Bs[row][col] = (gc < N) ? B[(size_t)(k0 + row) * N + gc] : 0.f;
      }
    }
    __syncthreads();
#pragma unroll
    for (int k = 0; k < 16; k++) {
      float a[4], b[4];
#pragma unroll
      for (int i = 0; i < 4; i++) a[i] = As[k][ty * 4 + i];
#pragma unroll
      for (int j = 0; j < 4; j++) b[j] = Bs[k][tx * 4 + j];
#pragma unroll
      for (int i = 0; i < 4; i++)
#pragma unroll
        for (int j = 0; j < 4; j++) acc[i][j] = fmaf(a[i], b[j], acc[i][j]);
    }
    __syncthreads();
  }
#pragma unroll
  for (int i = 0; i < 4; i++) {
    int gr = bm + ty * 4 + i;
#pragma unroll
    for (int j = 0; j < 4; j++) {
      int gc = bn + tx * 4 + j;
      if (gc < N) {
        float v = acc[i][j];
        if (bias) v += bias[gc];
        size_t o = (size_t)gr * N + gc;
        if (flags & 2) v += C[o];
        if (flags & 1) v = fmaxf(v, 0.f);
        C[o] = v;
      }
    }
  }
}

// ---------------- bf16 conversion pre-passes for the pred GEMM ----------------
__global__ void k_cvt_a(const float* __restrict__ x, unsigned short* __restrict__ y, int n4) {
  int i = blockIdx.x * blockDim.x + threadIdx.x;
  if (i < n4) {
    float4 v = *reinterpret_cast<const float4*>(x + (size_t)i * 4);
    unsigned short o[4] = {f2bf(v.x), f2bf(v.y), f2bf(v.z), f2bf(v.w)};
    *reinterpret_cast<uint2*>(y + (size_t)i * 4) = *reinterpret_cast<uint2*>(o);
  }
}

// pred_w [128][NCLS] fp32 -> Bt [NPAD][128] bf16 (transposed, zero-padded)
__global__ void k_cvt_bt(const float* __restrict__ Bsrc, unsigned short* __restrict__ Bt) {
  __shared__ float s[32][33];
  int n0 = blockIdx.x * 32, k0 = blockIdx.y * 32;
  int t = threadIdx.x;  // 256
  int c = t & 31, r8 = t >> 5;
#pragma unroll
  for (int r = 0; r < 4; r++) {
    int k = k0 + r8 + r * 8;
    int n = n0 + c;
    s[r8 + r * 8][c] = (n < NCLS) ? Bsrc[(size_t)k * NCLS + n] : 0.f;
  }
  __syncthreads();
#pragma unroll
  for (int r = 0; r < 4; r++) {
    int n = n0 + r8 + r * 8;  // row in Bt
    int k = k0 + c;
    Bt[(size_t)n * 128 + k] = f2bf(s[c][r8 + r * 8]);
  }
}

// ---------------- bf16 MFMA pred GEMM: C[4096][NCLS] = A @ Bt^T + bias ----------------
// A [4096][128] bf16, Bt [NPAD][128] bf16 (i.e. B transposed), K = 128
__global__ __launch_bounds__(256) void k_pred_gemm(const unsigned short* __restrict__ A,
                                                   const unsigned short* __restrict__ Bt,
                                                   const float* __restrict__ bias,
                                                   float* __restrict__ C) {
  __shared__ unsigned short As[128 * 128];  // 32 KB, XOR-swizzled 16B units
  __shared__ unsigned short Bs[128 * 128];  // 32 KB
  int m0 = blockIdx.y * 128;
  int n0 = blockIdx.x * 128;
  int tid = threadIdx.x;
  // stage both tiles: 2048 16B-units each, 256 threads x 8
#pragma unroll
  for (int i = 0; i < 8; i++) {
    int idx = tid + i * 256;
    int row = idx >> 4, ku = idx & 15;
    int sw = (ku ^ (row & 7)) * 8;
    ushort8 av = *reinterpret_cast<const ushort8*>(A + (size_t)(m0 + row) * 128 + ku * 8);
    *reinterpret_cast<ushort8*>(As + row * 128 + sw) = av;
    ushort8 bv = *reinterpret_cast<const ushort8*>(Bt + (size_t)(n0 + row) * 128 + ku * 8);
    *reinterpret_cast<ushort8*>(Bs + row * 128 + sw) = bv;
  }
  __syncthreads();
  int wave = tid >> 6, lane = tid & 63;
  int wm = (wave >> 1) * 64, wn = (wave & 1) * 64;
  int lr = lane & 15, lg = lane >> 4;
  f32x4 acc[4][4] = {};
#pragma unroll
  for (int kk = 0; kk < 4; kk++) {  // K-window of 32 per iter
    bf16x8 af[4], bfr[4];
#pragma unroll
    for (int mi = 0; mi < 4; mi++) {
      int row = wm + mi * 16 + lr;
      af[mi] = __builtin_bit_cast(
          bf16x8, *reinterpret_cast<const ushort8*>(As + row * 128 + (((kk * 4 + lg) ^ (row & 7)) * 8)));
      int col = wn + mi * 16 + lr;
      bfr[mi] = __builtin_bit_cast(
          bf16x8, *reinterpret_cast<const ushort8*>(Bs + col * 128 + (((kk * 4 + lg) ^ (col & 7)) * 8)));
    }
#pragma unroll
    for (int mi = 0; mi < 4; mi++)
#pragma unroll
      for (int ni = 0; ni < 4; ni++)
        acc[mi][ni] = __builtin_amdgcn_mfma_f32_16x16x32_bf16(af[mi], bfr[ni], acc[mi][ni], 0, 0, 0);
  }
  // C/D layout: col = lane&15, row = (lane>>4)*4 + reg   [measured m89]
#pragma unroll
  for (int mi = 0; mi < 4; mi++) {
#pragma unroll
    for (int ni = 0; ni < 4; ni++) {
      int col = n0 + wn + ni * 16 + lr;
      if (col < NCLS) {
        float bv = bias[col];
#pragma unroll
        for (int r = 0; r < 4; r++) {
          int row = m0 + wm + mi * 16 + lg * 4 + r;
          C[(size_t)row * NCLS + col] = acc[mi][ni][r] + bv;
        }
      }
    }
  }
}

// ---------------- degree / scatter helpers ----------------
__global__ void k_count(const int* __restrict__ idx, int* __restrict__ deg, int n) {
  for (int i = blockIdx.x * blockDim.x + threadIdx.x; i < n; i += gridDim.x * blockDim.x)
    atomicAdd(&deg[idx[i]], 1);
}

__global__ void k_dinv(const int* __restrict__ deg, float* __restrict__ dinv, int n, int self) {
  int i = blockIdx.x * blockDim.x + threadIdx.x;
  if (i < n) {
    int d = deg[i] + self;
    dinv[i] = d > 0 ? rsqrtf((float)d) : 0.f;
  }
}

__global__ void k_gcn_self(const float* __restrict__ h, const float* __restrict__ dinv,
                           float* __restrict__ agg, int logF, int n) {
  for (int i = blockIdx.x * blockDim.x + threadIdx.x; i < n; i += gridDim.x * blockDim.x) {
    float d = dinv[i >> logF];
    agg[i] = h[i] * d * d;
  }
}

__global__ void k_gcn_scatter(const float* __restrict__ h, const int* __restrict__ ei0,
                              const int* __restrict__ ei1, const float* __restrict__ dinv,
                              float* __restrict__ agg, int logF, int n) {
  int F1 = (1 << logF) - 1;
  for (int i = blockIdx.x * blockDim.x + threadIdx.x; i < n; i += gridDim.x * blockDim.x) {
    int e = i >> logF, f = i & F1;
    int r = ei0[e], c = ei1[e];
    atomicAdd(&agg[((size_t)c << logF) + f], h[((size_t)r << logF) + f] * dinv[r] * dinv[c]);
  }
}

__global__ void k_scatter_plain(const float* __restrict__ x, const int* __restrict__ ei0,
                                const int* __restrict__ ei1, float* __restrict__ agg, int n) {
  for (int i = blockIdx.x * blockDim.x + threadIdx.x; i < n; i += gridDim.x * blockDim.x) {
    int e = i >> 7, f = i & 127;
    int r = ei0[e], c = ei1[e];
    atomicAdd(&agg[((size_t)c << 7) + f], x[((size_t)r << 7) + f]);
  }
}

__global__ void k_scatter_cheb(const float* __restrict__ x, const int* __restrict__ ei0,
                               const int* __restrict__ ei1, const float* __restrict__ dinv,
                               float* __restrict__ agg, int n) {
  for (int i = blockIdx.x * blockDim.x + threadIdx.x; i < n; i += gridDim.x * blockDim.x) {
    int e = i >> 7, f = i & 127;
    int r = ei0[e], c = ei1[e];
    float w = -(dinv[r] * dinv[c]);
    atomicAdd(&agg[((size_t)c << 7) + f], x[((size_t)r << 7) + f] * w);
  }
}

__global__ void k_sage_div(float* __restrict__ agg, const int* __restrict__ cnt, int n) {
  for (int i = blockIdx.x * blockDim.x + threadIdx.x; i < n; i += gridDim.x * blockDim.x) {
    float c = (float)cnt[i >> 7];
    agg[i] = agg[i] / fmaxf(c, 1.f);
  }
}

// ---------------- batch norm ----------------
__global__ void k_bn_stats(const float* __restrict__ x, float* __restrict__ sum,
                           float* __restrict__ sumsq, int F) {
  int tid = threadIdx.x;
  int f = tid & (F - 1);
  int rstep = 256 / F;
  int r0 = tid / F;
  int base = blockIdx.x * 64;
  float s = 0.f, s2 = 0.f;
  for (int rr = r0; rr < 64; rr += rstep) {
    float v = x[(size_t)(base + rr) * F + f];
    s += v;
    s2 += v * v;
  }
  atomicAdd(&sum[f], s);
  atomicAdd(&sumsq[f], s2);
}

__global__ void k_bn_final(const float* __restrict__ sum, const float* __restrict__ sumsq,
                           const float* __restrict__ g, const float* __restrict__ be,
                           float* __restrict__ scale, float* __restrict__ shift, int F) {
  int f = blockIdx.x * blockDim.x + threadIdx.x;
  if (f < F) {
    float invM = 1.f / (float)NN;
    float mu = sum[f] * invM;
    float var = sumsq[f] * invM - mu * mu;
    float sc = g[f] * rsqrtf(var + 1e-5f);
    scale[f] = sc;
    shift[f] = be[f] - mu * sc;
  }
}

__global__ void k_bn_apply_relu(const float* __restrict__ x, const float* __restrict__ scale,
                                const float* __restrict__ shift, float* __restrict__ y,
                                int logF, int n) {
  int F1 = (1 << logF) - 1;
  for (int i = blockIdx.x * blockDim.x + threadIdx.x; i < n; i += gridDim.x * blockDim.x) {
    int f = i & F1;
    y[i] = fmaxf(x[i] * scale[f] + shift[f], 0.f);
  }
}

// ---------------- GAT ----------------
__global__ void k_gat_dots(const float* __restrict__ h, const float* __restrict__ asrc,
                           const float* __restrict__ adst, float* __restrict__ a_s,
                           float* __restrict__ a_d) {
  int n = blockIdx.x, l = threadIdx.x;  // 64 threads
  float h0 = h[n * 128 + l], h1 = h[n * 128 + 64 + l];
  float hs = h0 * asrc[l] + h1 * asrc[64 + l];
  float hd = h0 * adst[l] + h1 * adst[64 + l];
  for (int off = 32; off; off >>= 1) {
    hs += __shfl_down(hs, off, 64);
    hd += __shfl_down(hd, off, 64);
  }
  if (l == 0) {
    a_s[n] = hs;
    a_d[n] = hd;
  }
}

__global__ void k_gat_e(const int* __restrict__ ei0, const int* __restrict__ ei1,
                        const float* __restrict__ a_s, const float* __restrict__ a_d,
                        float* __restrict__ ee, unsigned* __restrict__ emax) {
  for (int e = blockIdx.x * blockDim.x + threadIdx.x; e < NE + NN; e += gridDim.x * blockDim.x) {
    int r, c;
    if (e < NE) { r = ei0[e]; c = ei1[e]; } else { r = c = e - NE; }
    float v = a_s[r] + a_d[c];
    v = v >= 0.f ? v : 0.2f * v;  // leaky_relu 0.2
    ee[e] = v;
    atomicMax(&emax[c], fkey(v));
  }
}

__global__ void k_gat_ex(const int* __restrict__ ei1, const unsigned* __restrict__ emax,
                         float* __restrict__ ee, float* __restrict__ denom) {
  for (int e = blockIdx.x * blockDim.x + threadIdx.x; e < NE + NN; e += gridDim.x * blockDim.x) {
    int c = (e < NE) ? ei1[e] : e - NE;
    float v = expf(ee[e] - fdec(emax[c]));
    ee[e] = v;
    atomicAdd(&denom[c], v);
  }
}

__global__ void k_gat_alpha(const int* __restrict__ ei1, const float* __restrict__ denom,
                            float* __restrict__ ee) {
  for (int e = blockIdx.x * blockDim.x + threadIdx.x; e < NE + NN; e += gridDim.x * blockDim.x) {
    int c = (e < NE) ? ei1[e] : e - NE;
    ee[e] = ee[e] / denom[c];
  }
}

__global__ void k_gat_scatter(const float* __restrict__ h, const int* __restrict__ ei0,
                              const int* __restrict__ ei1, const float* __restrict__ ee,
                              float* __restrict__ agg, int n) {
  for (int i = blockIdx.x * blockDim.x + threadIdx.x; i < n; i += gridDim.x * blockDim.x) {
    int e = i >> 7, f = i & 127;
    int r, c;
    if (e < NE) { r = ei0[e]; c = ei1[e]; } else { r = c = e - NE; }
    atomicAdd(&agg[((size_t)c << 7) + f], h[((size_t)r << 7) + f] * ee[e]);
  }
}

__global__ void k_elu_bias(const float* __restrict__ agg, const float* __restrict__ b,
                           float* __restrict__ out, int n) {
  for (int i = blockIdx.x * blockDim.x + threadIdx.x; i < n; i += gridDim.x * blockDim.x) {
    float v = agg[i] + b[i & 127];
    out[i] = v > 0.f ? v : expm1f(v);
  }
}

// ---------------- launch ----------------
static inline int cdiv(int a, int b) { return (a + b - 1) / b; }

extern "C" void kernel_launch(void* const* d_in, const int* in_sizes, int n_in,
                              void* d_out, int out_size, void* d_ws, size_t ws_size,
                              hipStream_t stream) {
  const int* ei0 = (const int*)d_in[0];
  const int* ei1 = ei0 + NE;
  const int* node_x = (const int*)d_in[1];
  const float* user_w = (const float*)d_in[2];
  const float* item_w = (const float*)d_in[3];
  const float* mlp_w1 = (const float*)d_in[4];
  const float* mlp_b1 = (const float*)d_in[5];
  const float* mlp_w2 = (const float*)d_in[6];
  const float* mlp_b2 = (const float*)d_in[7];
  const float* gcn_w1 = (const float*)d_in[8];
  // d_in[9] gcn_b1: cancelled by batch_norm mean subtraction
  const float* bn1_g = (const float*)d_in[10];
  const float* bn1_b = (const float*)d_in[11];
  const float* gcn_w2 = (const float*)d_in[12];
  // d_in[13] gcn_b2: cancelled by BN
  const float* bn2_g = (const float*)d_in[14];
  const float* bn2_b = (const float*)d_in[15];
  const float* sage_wl = (const float*)d_in[16];
  const float* sage_bl = (const float*)d_in[17];
  const float* sage_wr = (const float*)d_in[18];
  const float* cheb_w0 = (const float*)d_in[19];
  const float* cheb_w1 = (const float*)d_in[20];
  const float* cheb_b = (const float*)d_in[21];
  const float* gat1_w = (const float*)d_in[22];
  const float* gat1_as = (const float*)d_in[23];
  const float* gat1_ad = (const float*)d_in[24];
  const float* gat1_b = (const float*)d_in[25];
  const float* gat2_w = (const float*)d_in[26];
  const float* gat2_as = (const float*)d_in[27];
  const float* gat2_ad = (const float*)d_in[28];
  const float* gat2_b = (const float*)d_in[29];
  const float* pred_w = (const float*)d_in[30];
  const float* pred_b = (const float*)d_in[31];

  // ---- workspace layout (~39 MB) ----
  char* w = (char*)d_ws;
  size_t off = 0;
  auto alloc = [&](size_t bytes) -> char* {
    char* p = w + off;
    off = (off + bytes + 255) & ~(size_t)255;
    return p;
  };
  float* r1 = (float*)alloc((size_t)NN * 1024 * 4);  // x1, later h/agg/xa/xb
  float* x2 = (float*)alloc((size_t)NN * 512 * 4);
  float* x0 = (float*)alloc((size_t)NN * 128 * 4);
  float* ee = (float*)alloc((size_t)(NE + NN) * 4);
  int* deg = (int*)alloc(NN * 4);
  float* dinvA = (float*)alloc(NN * 4);
  float* dinvB = (float*)alloc(NN * 4);
  float* a_s = (float*)alloc(NN * 4);
  float* a_d = (float*)alloc(NN * 4);
  unsigned* emax = (unsigned*)alloc(NN * 4);
  float* denom = (float*)alloc(NN * 4);
  float* bsum = (float*)alloc(256 * 4);
  float* bsq = (float*)alloc(256 * 4);
  float* bscale = (float*)alloc(256 * 4);
  float* bshift = (float*)alloc(256 * 4);
  unsigned short* Abf = (unsigned short*)alloc((size_t)NN * 128 * 2);
  unsigned short* Btb = (unsigned short*)alloc((size_t)NPAD * 128 * 2);

  float* h = r1;  // 4096x256 max
  float* agg = r1 + NN * 256;
  float* xa = r1 + 2 * NN * 256;
  float* xb = r1 + 3 * NN * 256;

  const int GSB = 4096;

  auto gemm = [&](const float* A, const float* B, const float* bias, float* C,
                  int M, int N, int K, int flags) {
    dim3 g(cdiv(N, 64), M / 64), b(256);
    k_gemm<<<g, b, 0, stream>>>(A, B, bias, C, M, N, K, flags);
  };

  // pred_w transpose+convert can run up front
  k_cvt_bt<<<dim3(NPAD / 32, 4), 256, 0, stream>>>(pred_w, Btb);

  // stage 0: gather
  k_gather<<<NN, 128, 0, stream>>>(node_x, user_w, item_w, x0);
  // stage 1-2: MLP
  gemm(x0, mlp_w1, mlp_b1, r1, NN, 1024, 128, 1);
  gemm(r1, mlp_w2, mlp_b2, x2, NN, 512, 1024, 1);

  // ---- GCN1 (512 -> 256) ----
  gemm(x2, gcn_w1, nullptr, h, NN, 256, 512, 0);
  hipMemsetAsync(deg, 0, NN * 4, stream);
  k_count<<<512, 256, 0, stream>>>(ei1, deg, NE);
  k_dinv<<<cdiv(NN, 256), 256, 0, stream>>>(deg, dinvA, NN, 1);
  k_gcn_self<<<GSB, 256, 0, stream>>>(h, dinvA, agg, 8, NN * 256);
  k_gcn_scatter<<<GSB, 256, 0, stream>>>(h, ei0, ei1, dinvA, agg, 8, NE * 256);
  hipMemsetAsync(bsum, 0, 256 * 4, stream);
  hipMemsetAsync(bsq, 0, 256 * 4, stream);
  k_bn_stats<<<NN / 64, 256, 0, stream>>>(agg, bsum, bsq, 256);
  k_bn_final<<<1, 256, 0, stream>>>(bsum, bsq, bn1_g, bn1_b, bscale, bshift, 256);
  k_bn_apply_relu<<<GSB, 256, 0, stream>>>(agg, bscale, bshift, xa, 8, NN * 256);

  // ---- GCN2 (256 -> 128) ----
  gemm(xa, gcn_w2, nullptr, h, NN, 128, 256, 0);
  k_gcn_self<<<GSB, 256, 0, stream>>>(h, dinvA, agg, 7, NN * 128);
  k_gcn_scatter<<<GSB, 256, 0, stream>>>(h, ei0, ei1, dinvA, agg, 7, NE * 128);
  hipMemsetAsync(bsum, 0, 256 * 4, stream);
  hipMemsetAsync(bsq, 0, 256 * 4, stream);
  k_bn_stats<<<NN / 64, 256, 0, stream>>>(agg, bsum, bsq, 128);
  k_bn_final<<<1, 128, 0, stream>>>(bsum, bsq, bn2_g, bn2_b, bscale, bshift, 128);
  k_bn_apply_relu<<<GSB, 256, 0, stream>>>(agg, bscale, bshift, xb, 7, NN * 128);

  // ---- SAGE (x = xb) ----
  hipMemsetAsync(deg, 0, NN * 4, stream);
  k_count<<<512, 256, 0, stream>>>(ei1, deg, NE);
  hipMemsetAsync(agg, 0, (size_t)NN * 128 * 4, stream);
  k_scatter_plain<<<GSB, 256, 0, stream>>>(xb, ei0, ei1, agg, NE * 128);
  k_sage_div<<<GSB, 256, 0, stream>>>(agg, deg, NN * 128);
  gemm(agg, sage_wl, sage_bl, xa, NN, 128, 128, 0);
  gemm(xb, sage_wr, nullptr, xa, NN, 128, 128, 2 | 1);

  // ---- Cheb (x = xa) ----
  hipMemsetAsync(deg, 0, NN * 4, stream);
  k_count<<<512, 256, 0, stream>>>(ei0, deg, NE);
  k_dinv<<<cdiv(NN, 256), 256, 0, stream>>>(deg, dinvB, NN, 0);
  hipMemsetAsync(agg, 0, (size_t)NN * 128 * 4, stream);
  k_scatter_cheb<<<GSB, 256, 0, stream>>>(xa, ei0, ei1, dinvB, agg, NE * 128);
  gemm(xa, cheb_w0, cheb_b, xb, NN, 128, 128, 0);
  gemm(agg, cheb_w1, nullptr, xb, NN, 128, 128, 2 | 1);

  // ---- GAT1 (x = xb -> xa) ----
  gemm(xb, gat1_w, nullptr, h, NN, 128, 128, 0);
  k_gat_dots<<<NN, 64, 0, stream>>>(h, gat1_as, gat1_ad, a_s, a_d);
  hipMemsetAsync(emax, 0, NN * 4, stream);
  k_gat_e<<<512, 256, 0, stream>>>(ei0, ei1, a_s, a_d, ee, emax);
  hipMemsetAsync(denom, 0, NN * 4, stream);
  k_gat_ex<<<512, 256, 0, stream>>>(ei1, emax, ee, denom);
  k_gat_alpha<<<512, 256, 0, stream>>>(ei1, denom, ee);
  hipMemsetAsync(agg, 0, (size_t)NN * 128 * 4, stream);
  k_gat_scatter<<<GSB, 256, 0, stream>>>(h, ei0, ei1, ee, agg, (NE + NN) * 128);
  k_elu_bias<<<GSB, 256, 0, stream>>>(agg, gat1_b, xa, NN * 128);

  // ---- GAT2 (x = xa -> xb) ----
  gemm(xa, gat2_w, nullptr, h, NN, 128, 128, 0);
  k_gat_dots<<<NN, 64, 0, stream>>>(h, gat2_as, gat2_ad, a_s, a_d);
  hipMemsetAsync(emax, 0, NN * 4, stream);
  k_gat_e<<<512, 256, 0, stream>>>(ei0, ei1, a_s, a_d, ee, emax);
  hipMemsetAsync(denom, 0, NN * 4, stream);
  k_gat_ex<<<512, 256, 0, stream>>>(ei1, emax, ee, denom);
  k_gat_alpha<<<512, 256, 0, stream>>>(ei1, denom, ee);
  hipMemsetAsync(agg, 0, (size_t)NN * 128 * 4, stream);
  k_gat_scatter<<<GSB, 256, 0, stream>>>(h, ei0, ei1, ee, agg, (NE + NN) * 128);
  k_elu_bias<<<GSB, 256, 0, stream>>>(agg, gat2_b, xb, NN * 128);

  // ---- final prediction GEMM (bf16 MFMA) ----
  k_cvt_a<<<cdiv(NN * 128 / 4, 256), 256, 0, stream>>>(xb, Abf, NN * 128 / 4);
  k_pred_gemm<<<dim3(NPAD / 128, NN / 128), 256, 0, stream>>>(Abf, Btb, pred_b, (float*)d_out);
}

// Round 3
// 628.307 us; speedup vs baseline: 3.0714x; 1.9710x over previous
//
#include <hip/hip_runtime.h>
#include <math.h>

#define NN 4096
#define NE 131072
#define NCLS 41476
#define NPAD 41600  // 325 * 128

typedef __attribute__((ext_vector_type(8))) unsigned short ushort8;
typedef __attribute__((ext_vector_type(8))) __bf16 bf16x8;
typedef __attribute__((ext_vector_type(4))) float f32x4;

__device__ __forceinline__ unsigned short f2bf(float f) {
  unsigned u = __float_as_uint(f);
  unsigned r = u + 0x7fffu + ((u >> 16) & 1u);  // RNE
  return (unsigned short)(r >> 16);
}

// ---------------- gather + concat embeddings -> bf16 ----------------
__global__ void k_gather(const int* __restrict__ node_x, const float* __restrict__ uw,
                         const float* __restrict__ iw, unsigned short* __restrict__ x0) {
  int n = blockIdx.x, t = threadIdx.x;  // 128 threads
  int u = node_x[n * 2], it = node_x[n * 2 + 1];
  float v = (t < 64) ? uw[u * 64 + t] : iw[it * 64 + (t - 64)];
  x0[n * 128 + t] = f2bf(v);
}

// ---------------- generic weight transpose+convert: B[K][N] fp32 -> Bt[Npad][K] bf16 ----------------
__global__ void k_cvt_bt(const float* __restrict__ B, unsigned short* __restrict__ Bt,
                         int K, int N) {
  __shared__ float s[32][33];
  int n0 = blockIdx.x * 32, k0 = blockIdx.y * 32;
  int t = threadIdx.x;  // 256
  int c = t & 31, r8 = t >> 5;
#pragma unroll
  for (int r = 0; r < 4; r++) {
    int k = k0 + r8 + r * 8;
    int n = n0 + c;
    s[r8 + r * 8][c] = (n < N) ? B[(size_t)k * N + n] : 0.f;
  }
  __syncthreads();
#pragma unroll
  for (int r = 0; r < 4; r++) {
    int n = n0 + r8 + r * 8;
    int kq = k0 + c;
    Bt[(size_t)n * K + kq] = f2bf(s[c][r8 + r * 8]);
  }
}

__global__ void k_cvt_a(const float* __restrict__ x, unsigned short* __restrict__ y, int n4) {
  int i = blockIdx.x * blockDim.x + threadIdx.x;
  if (i < n4) {
    float4 v = *reinterpret_cast<const float4*>(x + (size_t)i * 4);
    unsigned short o[4] = {f2bf(v.x), f2bf(v.y), f2bf(v.z), f2bf(v.w)};
    *reinterpret_cast<uint2*>(y + (size_t)i * 4) = *reinterpret_cast<uint2*>(o);
  }
}

// ---------------- generic bf16 MFMA GEMM: C[M][N] = A[M][K] @ Bt[Npad][K]^T (+bias)(relu) ----------------
// M = 4096 (grid.y = 32), tile 128x128, K multiple of 128. OUTBF: 1 -> bf16 out, 0 -> fp32 out.
template <int OUTBF>
__global__ __launch_bounds__(256) void k_bgemm(const unsigned short* __restrict__ A,
                                               const unsigned short* __restrict__ Bt,
                                               const float* __restrict__ bias,
                                               void* __restrict__ Cv, int N, int K, int relu) {
  __shared__ unsigned short As[128 * 128];
  __shared__ unsigned short Bs[128 * 128];
  int m0 = blockIdx.y * 128;
  int n0 = blockIdx.x * 128;
  int tid = threadIdx.x;
  int wave = tid >> 6, lane = tid & 63;
  int wm = (wave >> 1) * 64, wn = (wave & 1) * 64;
  int lr = lane & 15, lg = lane >> 4;
  f32x4 acc[4][4] = {};
  for (int k0 = 0; k0 < K; k0 += 128) {
#pragma unroll
    for (int i = 0; i < 8; i++) {
      int idx = tid + i * 256;
      int row = idx >> 4, ku = idx & 15;
      int sw = (ku ^ (row & 7)) * 8;
      ushort8 av = *reinterpret_cast<const ushort8*>(A + (size_t)(m0 + row) * K + k0 + ku * 8);
      *reinterpret_cast<ushort8*>(As + row * 128 + sw) = av;
      ushort8 bv = *reinterpret_cast<const ushort8*>(Bt + (size_t)(n0 + row) * K + k0 + ku * 8);
      *reinterpret_cast<ushort8*>(Bs + row * 128 + sw) = bv;
    }
    __syncthreads();
#pragma unroll
    for (int kk = 0; kk < 4; kk++) {
      bf16x8 af[4], bfr[4];
#pragma unroll
      for (int mi = 0; mi < 4; mi++) {
        int row = wm + mi * 16 + lr;
        af[mi] = __builtin_bit_cast(
            bf16x8, *reinterpret_cast<const ushort8*>(As + row * 128 + (((kk * 4 + lg) ^ (row & 7)) * 8)));
        int col = wn + mi * 16 + lr;
        bfr[mi] = __builtin_bit_cast(
            bf16x8, *reinterpret_cast<const ushort8*>(Bs + col * 128 + (((kk * 4 + lg) ^ (col & 7)) * 8)));
      }
#pragma unroll
      for (int mi = 0; mi < 4; mi++)
#pragma unroll
        for (int ni = 0; ni < 4; ni++)
          acc[mi][ni] = __builtin_amdgcn_mfma_f32_16x16x32_bf16(af[mi], bfr[ni], acc[mi][ni], 0, 0, 0);
    }
    __syncthreads();
  }
  // C/D layout: col = lane&15, row = (lane>>4)*4 + reg
#pragma unroll
  for (int mi = 0; mi < 4; mi++) {
#pragma unroll
    for (int ni = 0; ni < 4; ni++) {
      int col = n0 + wn + ni * 16 + lr;
      if (col < N) {
        float bv = bias ? bias[col] : 0.f;
#pragma unroll
        for (int r = 0; r < 4; r++) {
          int row = m0 + wm + mi * 16 + lg * 4 + r;
          float v = acc[mi][ni][r] + bv;
          if (relu) v = fmaxf(v, 0.f);
          if (OUTBF)
            ((unsigned short*)Cv)[(size_t)row * N + col] = f2bf(v);
          else
            ((float*)Cv)[(size_t)row * N + col] = v;
        }
      }
    }
  }
}

// ---------------- fp32 GEMM (small 128-wide layers) ----------------
__global__ __launch_bounds__(256) void k_gemm(const float* __restrict__ A, const float* __restrict__ B,
                                              const float* __restrict__ bias, float* __restrict__ C,
                                              int M, int N, int K, int flags) {
  __shared__ float As[16][65];
  __shared__ float Bs[16][65];
  int bm = blockIdx.y * 64;
  int bn = blockIdx.x * 64;
  int tid = threadIdx.x;
  int tx = tid & 15, ty = tid >> 4;
  float acc[4][4] = {};
  for (int k0 = 0; k0 < K; k0 += 16) {
    {
      int row = tid >> 2;
      int kk = (tid & 3) * 4;
      const float4 av = *reinterpret_cast<const float4*>(A + (size_t)(bm + row) * K + k0 + kk);
      As[kk + 0][row] = av.x; As[kk + 1][row] = av.y; As[kk + 2][row] = av.z; As[kk + 3][row] = av.w;
    }
    {
      int col = tid & 63;
      int rb = tid >> 6;
      int gc = bn + col;
#pragma unroll
      for (int r = 0; r < 4; r++) {
        int row = rb + r * 4;
        Bs[row][col] = (gc < N) ? B[(size_t)(k0 + row) * N + gc] : 0.f;
      }
    }
    __syncthreads();
#pragma unroll
    for (int k = 0; k < 16; k++) {
      float a[4], b[4];
#pragma unroll
      for (int i = 0; i < 4; i++) a[i] = As[k][ty * 4 + i];
#pragma unroll
      for (int j = 0; j < 4; j++) b[j] = Bs[k][tx * 4 + j];
#pragma unroll
      for (int i = 0; i < 4; i++)
#pragma unroll
        for (int j = 0; j < 4; j++) acc[i][j] = fmaf(a[i], b[j], acc[i][j]);
    }
    __syncthreads();
  }
#pragma unroll
  for (int i = 0; i < 4; i++) {
    int gr = bm + ty * 4 + i;
#pragma unroll
    for (int j = 0; j < 4; j++) {
      int gc = bn + tx * 4 + j;
      if (gc < N) {
        float v = acc[i][j];
        if (bias) v += bias[gc];
        size_t o = (size_t)gr * N + gc;
        if (flags & 2) v += C[o];
        if (flags & 1) v = fmaxf(v, 0.f);
        C[o] = v;
      }
    }
  }
}

// ---------------- CSR build ----------------
__global__ void k_count(const int* __restrict__ idx, int* __restrict__ deg, int n) {
  for (int i = blockIdx.x * blockDim.x + threadIdx.x; i < n; i += gridDim.x * blockDim.x)
    atomicAdd(&deg[idx[i]], 1);
}

__global__ void k_dinv(const int* __restrict__ deg, float* __restrict__ dinv, int n, int self) {
  int i = blockIdx.x * blockDim.x + threadIdx.x;
  if (i < n) {
    int d = deg[i] + self;
    dinv[i] = d > 0 ? rsqrtf((float)d) : 0.f;
  }
}

__global__ void k_scan4096(const int* __restrict__ deg, int* __restrict__ rowptr,
                           int* __restrict__ cursor) {
  __shared__ int s[1024];
  int t = threadIdx.x;
  int4 d = *reinterpret_cast<const int4*>(deg + t * 4);
  int sum = d.x + d.y + d.z + d.w;
  s[t] = sum;
  __syncthreads();
  for (int off = 1; off < 1024; off <<= 1) {
    int x = (t >= off) ? s[t - off] : 0;
    __syncthreads();
    s[t] += x;
    __syncthreads();
  }
  int base = s[t] - sum;  // exclusive
  int4 o;
  o.x = base; o.y = base + d.x; o.z = o.y + d.y; o.w = o.z + d.z;
  *reinterpret_cast<int4*>(rowptr + t * 4) = o;
  *reinterpret_cast<int4*>(cursor + t * 4) = o;
  if (t == 1023) rowptr[4096] = base + sum;
}

__global__ void k_fill(const int* __restrict__ ei0, const int* __restrict__ ei1,
                       int* __restrict__ cursor, int* __restrict__ csr_src) {
  int e = blockIdx.x * blockDim.x + threadIdx.x;
  if (e < NE) {
    int pos = atomicAdd(&cursor[ei1[e]], 1);
    csr_src[pos] = ei0[e];
  }
}

// ---------------- CSR aggregations (1 block per destination node) ----------------
// GCN: out[c] = dc * ( h[c]*dc + sum_j h[src_j]*dinv[src_j] )
template <int LOGF>
__global__ void k_gcn_agg(const float* __restrict__ h, const int* __restrict__ rowptr,
                          const int* __restrict__ csr_src, const float* __restrict__ dinv,
                          float* __restrict__ out) {
  __shared__ int sld[128];
  __shared__ float wld[128];
  int c = blockIdx.x, f = threadIdx.x;  // blockDim = 1<<LOGF
  float dc = dinv[c];
  int r0 = rowptr[c], r1 = rowptr[c + 1];
  float acc = h[((size_t)c << LOGF) + f] * dc;
  for (int base = r0; base < r1; base += 128) {
    int nb = min(128, r1 - base);
    if (f < nb) {
      int s = csr_src[base + f];
      sld[f] = s;
      wld[f] = dinv[s];
    }
    __syncthreads();
    for (int i = 0; i < nb; i++) acc += h[((size_t)sld[i] << LOGF) + f] * wld[i];
    __syncthreads();
  }
  out[((size_t)c << LOGF) + f] = acc * dc;
}

// SAGE: out[c] = sum_j x[src_j] / max(deg,1)
__global__ void k_sage_agg(const float* __restrict__ x, const int* __restrict__ rowptr,
                           const int* __restrict__ csr_src, float* __restrict__ out) {
  __shared__ int sld[128];
  int c = blockIdx.x, f = threadIdx.x;  // 128
  int r0 = rowptr[c], r1 = rowptr[c + 1];
  float acc = 0.f;
  for (int base = r0; base < r1; base += 128) {
    int nb = min(128, r1 - base);
    if (f < nb) sld[f] = csr_src[base + f];
    __syncthreads();
    for (int i = 0; i < nb; i++) acc += x[((size_t)sld[i] << 7) + f];
    __syncthreads();
  }
  out[((size_t)c << 7) + f] = acc / fmaxf((float)(r1 - r0), 1.f);
}

// Cheb: out[c] = -dinv0[c] * sum_j x[src_j]*dinv0[src_j]
__global__ void k_cheb_agg(const float* __restrict__ x, const int* __restrict__ rowptr,
                           const int* __restrict__ csr_src, const float* __restrict__ dinv0,
                           float* __restrict__ out) {
  __shared__ int sld[128];
  __shared__ float wld[128];
  int c = blockIdx.x, f = threadIdx.x;  // 128
  int r0 = rowptr[c], r1 = rowptr[c + 1];
  float acc = 0.f;
  for (int base = r0; base < r1; base += 128) {
    int nb = min(128, r1 - base);
    if (f < nb) {
      int s = csr_src[base + f];
      sld[f] = s;
      wld[f] = dinv0[s];
    }
    __syncthreads();
    for (int i = 0; i < nb; i++) acc += x[((size_t)sld[i] << 7) + f] * wld[i];
    __syncthreads();
  }
  out[((size_t)c << 7) + f] = -acc * dinv0[c];
}

// GAT: full edge-softmax + weighted aggregation + self loop + bias + ELU, one pass
__global__ void k_gat_agg(const float* __restrict__ h, const int* __restrict__ rowptr,
                          const int* __restrict__ csr_src, const float* __restrict__ a_s,
                          const float* __restrict__ a_d, const float* __restrict__ bias,
                          float* __restrict__ out) {
  __shared__ int sld[128];
  __shared__ float eld[128];
  int c = blockIdx.x, f = threadIdx.x;  // 128
  int r0 = rowptr[c], r1 = rowptr[c + 1];
  float adc = a_d[c];
  float es = a_s[c] + adc;
  es = es >= 0.f ? es : 0.2f * es;  // self-loop leaky
  float m = es;
  for (int base = r0; base < r1; base += 128) {
    int nb = min(128, r1 - base);
    if (f < nb) {
      int s = csr_src[base + f];
      sld[f] = s;
      float v = a_s[s] + adc;
      eld[f] = v >= 0.f ? v : 0.2f * v;
    }
    __syncthreads();
    for (int i = 0; i < nb; i++) m = fmaxf(m, eld[i]);
    __syncthreads();
  }
  float den = expf(es - m);
  float acc = den * h[((size_t)c << 7) + f];
  for (int base = r0; base < r1; base += 128) {
    int nb = min(128, r1 - base);
    if (f < nb) {
      int s = csr_src[base + f];
      sld[f] = s;
      float v = a_s[s] + adc;
      v = v >= 0.f ? v : 0.2f * v;
      eld[f] = expf(v - m);
    }
    __syncthreads();
    for (int i = 0; i < nb; i++) {
      float w = eld[i];
      acc += w * h[((size_t)sld[i] << 7) + f];
      den += w;
    }
    __syncthreads();
  }
  float v = acc / den + bias[f];
  out[((size_t)c << 7) + f] = v > 0.f ? v : expm1f(v);
}

// ---------------- batch norm ----------------
__global__ void k_bn_stats(const float* __restrict__ x, float* __restrict__ sum,
                           float* __restrict__ sumsq, int F) {
  int tid = threadIdx.x;
  int f = tid & (F - 1);
  int rstep = 256 / F;
  int r0 = tid / F;
  int base = blockIdx.x * 64;
  float s = 0.f, s2 = 0.f;
  for (int rr = r0; rr < 64; rr += rstep) {
    float v = x[(size_t)(base + rr) * F + f];
    s += v;
    s2 += v * v;
  }
  atomicAdd(&sum[f], s);
  atomicAdd(&sumsq[f], s2);
}

__global__ void k_bn_final(const float* __restrict__ sum, const float* __restrict__ sumsq,
                           const float* __restrict__ g, const float* __restrict__ be,
                           float* __restrict__ scale, float* __restrict__ shift, int F) {
  int f = blockIdx.x * blockDim.x + threadIdx.x;
  if (f < F) {
    float invM = 1.f / (float)NN;
    float mu = sum[f] * invM;
    float var = sumsq[f] * invM - mu * mu;
    float sc = g[f] * rsqrtf(var + 1e-5f);
    scale[f] = sc;
    shift[f] = be[f] - mu * sc;
  }
}

__global__ void k_bn_apply_relu(const float* __restrict__ x, const float* __restrict__ scale,
                                const float* __restrict__ shift, float* __restrict__ y,
                                int logF, int n) {
  int F1 = (1 << logF) - 1;
  for (int i = blockIdx.x * blockDim.x + threadIdx.x; i < n; i += gridDim.x * blockDim.x) {
    int f = i & F1;
    y[i] = fmaxf(x[i] * scale[f] + shift[f], 0.f);
  }
}

// ---------------- GAT per-node dot products ----------------
__global__ void k_gat_dots(const float* __restrict__ h, const float* __restrict__ asrc,
                           const float* __restrict__ adst, float* __restrict__ a_s,
                           float* __restrict__ a_d) {
  int n = blockIdx.x, l = threadIdx.x;  // 64 threads
  float h0 = h[n * 128 + l], h1 = h[n * 128 + 64 + l];
  float hs = h0 * asrc[l] + h1 * asrc[64 + l];
  float hd = h0 * adst[l] + h1 * adst[64 + l];
  for (int off = 32; off; off >>= 1) {
    hs += __shfl_down(hs, off, 64);
    hd += __shfl_down(hd, off, 64);
  }
  if (l == 0) {
    a_s[n] = hs;
    a_d[n] = hd;
  }
}

// ---------------- launch ----------------
static inline int cdiv(int a, int b) { return (a + b - 1) / b; }

extern "C" void kernel_launch(void* const* d_in, const int* in_sizes, int n_in,
                              void* d_out, int out_size, void* d_ws, size_t ws_size,
                              hipStream_t stream) {
  const int* ei0 = (const int*)d_in[0];
  const int* ei1 = ei0 + NE;
  const int* node_x = (const int*)d_in[1];
  const float* user_w = (const float*)d_in[2];
  const float* item_w = (const float*)d_in[3];
  const float* mlp_w1 = (const float*)d_in[4];
  const float* mlp_b1 = (const float*)d_in[5];
  const float* mlp_w2 = (const float*)d_in[6];
  const float* mlp_b2 = (const float*)d_in[7];
  const float* gcn_w1 = (const float*)d_in[8];
  // d_in[9] gcn_b1: cancelled by batch_norm mean subtraction
  const float* bn1_g = (const float*)d_in[10];
  const float* bn1_b = (const float*)d_in[11];
  const float* gcn_w2 = (const float*)d_in[12];
  // d_in[13] gcn_b2: cancelled by BN
  const float* bn2_g = (const float*)d_in[14];
  const float* bn2_b = (const float*)d_in[15];
  const float* sage_wl = (const float*)d_in[16];
  const float* sage_bl = (const float*)d_in[17];
  const float* sage_wr = (const float*)d_in[18];
  const float* cheb_w0 = (const float*)d_in[19];
  const float* cheb_w1 = (const float*)d_in[20];
  const float* cheb_b = (const float*)d_in[21];
  const float* gat1_w = (const float*)d_in[22];
  const float* gat1_as = (const float*)d_in[23];
  const float* gat1_ad = (const float*)d_in[24];
  const float* gat1_b = (const float*)d_in[25];
  const float* gat2_w = (const float*)d_in[26];
  const float* gat2_as = (const float*)d_in[27];
  const float* gat2_ad = (const float*)d_in[28];
  const float* gat2_b = (const float*)d_in[29];
  const float* pred_w = (const float*)d_in[30];
  const float* pred_b = (const float*)d_in[31];

  // ---- workspace layout (~43 MB) ----
  char* w = (char*)d_ws;
  size_t off = 0;
  auto alloc = [&](size_t bytes) -> char* {
    char* p = w + off;
    off = (off + bytes + 255) & ~(size_t)255;
    return p;
  };
  float* h = (float*)alloc((size_t)NN * 256 * 4);
  float* agg = (float*)alloc((size_t)NN * 256 * 4);
  float* xa = (float*)alloc((size_t)NN * 256 * 4);
  float* xb = (float*)alloc((size_t)NN * 256 * 4);
  unsigned short* x0b = (unsigned short*)alloc((size_t)NN * 128 * 2);
  unsigned short* x1b = (unsigned short*)alloc((size_t)NN * 1024 * 2);
  unsigned short* x2b = (unsigned short*)alloc((size_t)NN * 512 * 2);
  unsigned short* w1t = (unsigned short*)alloc((size_t)1024 * 128 * 2);
  unsigned short* w2t = (unsigned short*)alloc((size_t)512 * 1024 * 2);
  unsigned short* g1t = (unsigned short*)alloc((size_t)256 * 512 * 2);
  unsigned short* predT = (unsigned short*)alloc((size_t)NPAD * 128 * 2);
  unsigned short* Abf = (unsigned short*)alloc((size_t)NN * 128 * 2);
  int* deg1 = (int*)alloc(NN * 4);
  int* deg0 = (int*)alloc(NN * 4);
  int* rowptr = (int*)alloc((NN + 1) * 4);
  int* cursor = (int*)alloc(NN * 4);
  int* csr_src = (int*)alloc(NE * 4);
  float* dinvA = (float*)alloc(NN * 4);
  float* dinv0 = (float*)alloc(NN * 4);
  float* a_s = (float*)alloc(NN * 4);
  float* a_d = (float*)alloc(NN * 4);
  float* bsum = (float*)alloc(256 * 4);
  float* bsq = (float*)alloc(256 * 4);
  float* bscale = (float*)alloc(256 * 4);
  float* bshift = (float*)alloc(256 * 4);

  auto gemm = [&](const float* A, const float* B, const float* bias, float* C,
                  int M, int N, int K, int flags) {
    dim3 g(cdiv(N, 64), M / 64), b(256);
    k_gemm<<<g, b, 0, stream>>>(A, B, bias, C, M, N, K, flags);
  };

  // ---- CSR build + degrees (independent of features) ----
  hipMemsetAsync(deg1, 0, NN * 4, stream);
  hipMemsetAsync(deg0, 0, NN * 4, stream);
  k_count<<<512, 256, 0, stream>>>(ei1, deg1, NE);
  k_count<<<512, 256, 0, stream>>>(ei0, deg0, NE);
  k_scan4096<<<1, 1024, 0, stream>>>(deg1, rowptr, cursor);
  k_fill<<<cdiv(NE, 256), 256, 0, stream>>>(ei0, ei1, cursor, csr_src);
  k_dinv<<<cdiv(NN, 256), 256, 0, stream>>>(deg1, dinvA, NN, 1);  // GCN: deg over col + self
  k_dinv<<<cdiv(NN, 256), 256, 0, stream>>>(deg0, dinv0, NN, 0);  // Cheb: deg over row

  // ---- weight conversions ----
  k_cvt_bt<<<dim3(1024 / 32, 128 / 32), 256, 0, stream>>>(mlp_w1, w1t, 128, 1024);
  k_cvt_bt<<<dim3(512 / 32, 1024 / 32), 256, 0, stream>>>(mlp_w2, w2t, 1024, 512);
  k_cvt_bt<<<dim3(256 / 32, 512 / 32), 256, 0, stream>>>(gcn_w1, g1t, 512, 256);
  k_cvt_bt<<<dim3(NPAD / 32, 128 / 32), 256, 0, stream>>>(pred_w, predT, 128, NCLS);

  // ---- trunk ----
  k_gather<<<NN, 128, 0, stream>>>(node_x, user_w, item_w, x0b);
  k_bgemm<1><<<dim3(8, 32), 256, 0, stream>>>(x0b, w1t, mlp_b1, x1b, 1024, 128, 1);
  k_bgemm<1><<<dim3(4, 32), 256, 0, stream>>>(x1b, w2t, mlp_b2, x2b, 512, 1024, 1);

  // GCN1 (512 -> 256)
  k_bgemm<0><<<dim3(2, 32), 256, 0, stream>>>(x2b, g1t, nullptr, h, 256, 512, 0);
  k_gcn_agg<8><<<NN, 256, 0, stream>>>(h, rowptr, csr_src, dinvA, agg);
  hipMemsetAsync(bsum, 0, 256 * 4, stream);
  hipMemsetAsync(bsq, 0, 256 * 4, stream);
  k_bn_stats<<<NN / 64, 256, 0, stream>>>(agg, bsum, bsq, 256);
  k_bn_final<<<1, 256, 0, stream>>>(bsum, bsq, bn1_g, bn1_b, bscale, bshift, 256);
  k_bn_apply_relu<<<4096, 256, 0, stream>>>(agg, bscale, bshift, xa, 8, NN * 256);

  // GCN2 (256 -> 128)
  gemm(xa, gcn_w2, nullptr, h, NN, 128, 256, 0);
  k_gcn_agg<7><<<NN, 128, 0, stream>>>(h, rowptr, csr_src, dinvA, agg);
  hipMemsetAsync(bsum, 0, 256 * 4, stream);
  hipMemsetAsync(bsq, 0, 256 * 4, stream);
  k_bn_stats<<<NN / 64, 256, 0, stream>>>(agg, bsum, bsq, 128);
  k_bn_final<<<1, 128, 0, stream>>>(bsum, bsq, bn2_g, bn2_b, bscale, bshift, 128);
  k_bn_apply_relu<<<4096, 256, 0, stream>>>(agg, bscale, bshift, xb, 7, NN * 128);

  // SAGE (x = xb -> xa)
  k_sage_agg<<<NN, 128, 0, stream>>>(xb, rowptr, csr_src, agg);
  gemm(agg, sage_wl, sage_bl, xa, NN, 128, 128, 0);
  gemm(xb, sage_wr, nullptr, xa, NN, 128, 128, 2 | 1);

  // Cheb (x = xa -> xb)
  k_cheb_agg<<<NN, 128, 0, stream>>>(xa, rowptr, csr_src, dinv0, agg);
  gemm(xa, cheb_w0, cheb_b, xb, NN, 128, 128, 0);
  gemm(agg, cheb_w1, nullptr, xb, NN, 128, 128, 2 | 1);

  // GAT1 (x = xb -> xa)
  gemm(xb, gat1_w, nullptr, h, NN, 128, 128, 0);
  k_gat_dots<<<NN, 64, 0, stream>>>(h, gat1_as, gat1_ad, a_s, a_d);
  k_gat_agg<<<NN, 128, 0, stream>>>(h, rowptr, csr_src, a_s, a_d, gat1_b, xa);

  // GAT2 (x = xa -> xb)
  gemm(xa, gat2_w, nullptr, h, NN, 128, 128, 0);
  k_gat_dots<<<NN, 64, 0, stream>>>(h, gat2_as, gat2_ad, a_s, a_d);
  k_gat_agg<<<NN, 128, 0, stream>>>(h, rowptr, csr_src, a_s, a_d, gat2_b, xb);

  // ---- final prediction GEMM (bf16 MFMA) ----
  k_cvt_a<<<cdiv(NN * 128 / 4, 256), 256, 0, stream>>>(xb, Abf, NN * 128 / 4);
  k_bgemm<0><<<dim3(NPAD / 128, 32), 256, 0, stream>>>(Abf, predT, pred_b, (float*)d_out, NCLS, 128, 0);
}

// Round 4
// 510.043 us; speedup vs baseline: 3.7836x; 1.2319x over previous
//
#include <hip/hip_runtime.h>
#include <math.h>

#define NN 4096
#define NE 131072
#define NCLS 41476
#define NPAD 41600  // 325 * 128

typedef __attribute__((ext_vector_type(8))) unsigned short ushort8;
typedef __attribute__((ext_vector_type(8))) __bf16 bf16x8;
typedef __attribute__((ext_vector_type(4))) float f32x4;

__device__ __forceinline__ unsigned short f2bf(float f) {
  unsigned u = __float_as_uint(f);
  unsigned r = u + 0x7fffu + ((u >> 16) & 1u);  // RNE
  return (unsigned short)(r >> 16);
}
__device__ __forceinline__ float bf2f(unsigned short u) {
  return __uint_as_float(((unsigned)u) << 16);
}

// ---------------- gather + concat embeddings -> bf16 ----------------
__global__ void k_gather(const int* __restrict__ node_x, const float* __restrict__ uw,
                         const float* __restrict__ iw, unsigned short* __restrict__ x0) {
  int n = blockIdx.x, t = threadIdx.x;  // 128 threads
  int u = node_x[n * 2], it = node_x[n * 2 + 1];
  float v = (t < 64) ? uw[u * 64 + t] : iw[it * 64 + (t - 64)];
  x0[n * 128 + t] = f2bf(v);
}

// ---------------- ALL weight transposes in one launch ----------------
// B[K][N] fp32 -> dst[n][ld] bf16 at column offset koff (rows beyond N zero-padded)
struct CvtDesc { const float* src; unsigned short* dst; int K, N, ld, koff, tile0, ntx; };
struct CvtArgs { CvtDesc d[11]; };

__global__ void k_cvt_all(CvtArgs a) {
  __shared__ float s[32][33];
  int b = blockIdx.x;
  int di = 0;
#pragma unroll
  for (int i = 1; i < 11; i++)
    if (a.d[i].tile0 <= b) di = i;
  const CvtDesc dd = a.d[di];
  int t = b - dd.tile0;
  int n0 = (t % dd.ntx) * 32, k0 = (t / dd.ntx) * 32;
  int tt = threadIdx.x, c = tt & 31, r8 = tt >> 5;
#pragma unroll
  for (int r = 0; r < 4; r++) {
    int k = k0 + r8 + r * 8, n = n0 + c;
    s[r8 + r * 8][c] = (n < dd.N) ? dd.src[(size_t)k * dd.N + n] : 0.f;
  }
  __syncthreads();
#pragma unroll
  for (int r = 0; r < 4; r++) {
    int n = n0 + r8 + r * 8, k = k0 + c;
    dd.dst[(size_t)n * dd.ld + dd.koff + k] = f2bf(s[c][r8 + r * 8]);
  }
}

// ---------------- bf16 MFMA GEMM, 128x128 tile (MLP + pred) ----------------
template <int OUTBF>
__global__ __launch_bounds__(256) void k_bgemm(const unsigned short* __restrict__ A,
                                               const unsigned short* __restrict__ Bt,
                                               const float* __restrict__ bias,
                                               void* __restrict__ Cv, int N, int K, int relu) {
  __shared__ unsigned short As[128 * 128];
  __shared__ unsigned short Bs[128 * 128];
  int m0 = blockIdx.y * 128;
  int n0 = blockIdx.x * 128;
  int tid = threadIdx.x;
  int wave = tid >> 6, lane = tid & 63;
  int wm = (wave >> 1) * 64, wn = (wave & 1) * 64;
  int lr = lane & 15, lg = lane >> 4;
  f32x4 acc[4][4] = {};
  for (int k0 = 0; k0 < K; k0 += 128) {
#pragma unroll
    for (int i = 0; i < 8; i++) {
      int idx = tid + i * 256;
      int row = idx >> 4, ku = idx & 15;
      int sw = (ku ^ (row & 7)) * 8;
      *reinterpret_cast<ushort8*>(As + row * 128 + sw) =
          *reinterpret_cast<const ushort8*>(A + (size_t)(m0 + row) * K + k0 + ku * 8);
      *reinterpret_cast<ushort8*>(Bs + row * 128 + sw) =
          *reinterpret_cast<const ushort8*>(Bt + (size_t)(n0 + row) * K + k0 + ku * 8);
    }
    __syncthreads();
#pragma unroll
    for (int kk = 0; kk < 4; kk++) {
      bf16x8 af[4], bfr[4];
#pragma unroll
      for (int mi = 0; mi < 4; mi++) {
        int row = wm + mi * 16 + lr;
        af[mi] = __builtin_bit_cast(
            bf16x8, *reinterpret_cast<const ushort8*>(As + row * 128 + (((kk * 4 + lg) ^ (row & 7)) * 8)));
        int col = wn + mi * 16 + lr;
        bfr[mi] = __builtin_bit_cast(
            bf16x8, *reinterpret_cast<const ushort8*>(Bs + col * 128 + (((kk * 4 + lg) ^ (col & 7)) * 8)));
      }
#pragma unroll
      for (int mi = 0; mi < 4; mi++)
#pragma unroll
        for (int ni = 0; ni < 4; ni++)
          acc[mi][ni] = __builtin_amdgcn_mfma_f32_16x16x32_bf16(af[mi], bfr[ni], acc[mi][ni], 0, 0, 0);
    }
    __syncthreads();
  }
#pragma unroll
  for (int mi = 0; mi < 4; mi++) {
#pragma unroll
    for (int ni = 0; ni < 4; ni++) {
      int col = n0 + wn + ni * 16 + lr;
      if (col < N) {
        float bv = bias ? bias[col] : 0.f;
#pragma unroll
        for (int r = 0; r < 4; r++) {
          int row = m0 + wm + mi * 16 + lg * 4 + r;
          float v = acc[mi][ni][r] + bv;
          if (relu) v = fmaxf(v, 0.f);
          if (OUTBF)
            ((unsigned short*)Cv)[(size_t)row * N + col] = f2bf(v);
          else
            ((float*)Cv)[(size_t)row * N + col] = v;
        }
      }
    }
  }
}

// ---------------- bf16 MFMA GEMM, 32x128 tile (skinny trunk layers) ----------------
// C[row][ldC] bf16 = A[M][K] @ Bt[N][K]^T (+bias)(relu). Grid (N/128, M/32), 256 thr.
__global__ __launch_bounds__(256) void k_bgemm_s(const unsigned short* __restrict__ A,
                                                 const unsigned short* __restrict__ Bt,
                                                 const float* __restrict__ bias,
                                                 unsigned short* __restrict__ C, int ldC,
                                                 int K, int relu) {
  __shared__ unsigned short As[32 * 64];
  __shared__ unsigned short Bs[128 * 64];
  int m0 = blockIdx.y * 32;
  int n0 = blockIdx.x * 128;
  int tid = threadIdx.x;
  int wave = tid >> 6, lane = tid & 63;
  int wn = wave * 32;
  int lr = lane & 15, lg = lane >> 4;
  f32x4 acc[2][2] = {};
  for (int k0 = 0; k0 < K; k0 += 64) {
    {
      int row = tid >> 3, u = tid & 7, sw = (u ^ (row & 7)) * 8;
      *reinterpret_cast<ushort8*>(As + row * 64 + sw) =
          *reinterpret_cast<const ushort8*>(A + (size_t)(m0 + row) * K + k0 + u * 8);
    }
#pragma unroll
    for (int i = 0; i < 4; i++) {
      int idx = tid + i * 256;
      int row = idx >> 3, u = idx & 7, sw = (u ^ (row & 7)) * 8;
      *reinterpret_cast<ushort8*>(Bs + row * 64 + sw) =
          *reinterpret_cast<const ushort8*>(Bt + (size_t)(n0 + row) * K + k0 + u * 8);
    }
    __syncthreads();
#pragma unroll
    for (int kk = 0; kk < 2; kk++) {
      bf16x8 af[2], bfr[2];
#pragma unroll
      for (int mi = 0; mi < 2; mi++) {
        int row = mi * 16 + lr;
        af[mi] = __builtin_bit_cast(
            bf16x8, *reinterpret_cast<const ushort8*>(As + row * 64 + (((kk * 4 + lg) ^ (row & 7)) * 8)));
        int col = wn + mi * 16 + lr;
        bfr[mi] = __builtin_bit_cast(
            bf16x8, *reinterpret_cast<const ushort8*>(Bs + col * 64 + (((kk * 4 + lg) ^ (col & 7)) * 8)));
      }
#pragma unroll
      for (int mi = 0; mi < 2; mi++)
#pragma unroll
        for (int ni = 0; ni < 2; ni++)
          acc[mi][ni] = __builtin_amdgcn_mfma_f32_16x16x32_bf16(af[mi], bfr[ni], acc[mi][ni], 0, 0, 0);
    }
    __syncthreads();
  }
#pragma unroll
  for (int mi = 0; mi < 2; mi++) {
#pragma unroll
    for (int ni = 0; ni < 2; ni++) {
      int col = n0 + wn + ni * 16 + lr;
      float bv = bias ? bias[col] : 0.f;
#pragma unroll
      for (int r = 0; r < 4; r++) {
        int row = m0 + mi * 16 + lg * 4 + r;
        float v = acc[mi][ni][r] + bv;
        if (relu) v = fmaxf(v, 0.f);
        C[(size_t)row * ldC + col] = f2bf(v);
      }
    }
  }
}

// ---------------- CSR build ----------------
__global__ void k_count2(const int* __restrict__ ei, int* __restrict__ deg0,
                         int* __restrict__ deg1) {
  for (int i = blockIdx.x * blockDim.x + threadIdx.x; i < 2 * NE; i += gridDim.x * blockDim.x) {
    int v = ei[i];
    atomicAdd((i < NE ? deg0 : deg1) + v, 1);
  }
}

__global__ void k_dinv(const int* __restrict__ deg, float* __restrict__ dinv, int n, int self) {
  int i = blockIdx.x * blockDim.x + threadIdx.x;
  if (i < n) {
    int d = deg[i] + self;
    dinv[i] = d > 0 ? rsqrtf((float)d) : 0.f;
  }
}

__global__ void k_scan4096(const int* __restrict__ deg, int* __restrict__ rowptr,
                           int* __restrict__ cursor, float* __restrict__ dinvA) {
  __shared__ int s[1024];
  int t = threadIdx.x;
  int4 d = *reinterpret_cast<const int4*>(deg + t * 4);
  float4 dv;
  dv.x = rsqrtf((float)(d.x + 1));
  dv.y = rsqrtf((float)(d.y + 1));
  dv.z = rsqrtf((float)(d.z + 1));
  dv.w = rsqrtf((float)(d.w + 1));
  *reinterpret_cast<float4*>(dinvA + t * 4) = dv;
  int sum = d.x + d.y + d.z + d.w;
  s[t] = sum;
  __syncthreads();
  for (int off = 1; off < 1024; off <<= 1) {
    int x = (t >= off) ? s[t - off] : 0;
    __syncthreads();
    s[t] += x;
    __syncthreads();
  }
  int base = s[t] - sum;  // exclusive
  int4 o;
  o.x = base; o.y = base + d.x; o.z = o.y + d.y; o.w = o.z + d.z;
  *reinterpret_cast<int4*>(rowptr + t * 4) = o;
  *reinterpret_cast<int4*>(cursor + t * 4) = o;
  if (t == 1023) rowptr[4096] = base + sum;
}

__global__ void k_fill(const int* __restrict__ ei0, const int* __restrict__ ei1,
                       int* __restrict__ cursor, int* __restrict__ csr_src) {
  int e = blockIdx.x * blockDim.x + threadIdx.x;
  if (e < NE) {
    int pos = atomicAdd(&cursor[ei1[e]], 1);
    csr_src[pos] = ei0[e];
  }
}

// ---------------- CSR aggregations (bf16 features, fp32 accum) ----------------
// GCN: out[c] = dc * ( h[c]*dc + sum_j h[src_j]*dinv[src_j] ), fp32 out (feeds BN)
template <int LOGF>
__global__ void k_gcn_agg(const unsigned short* __restrict__ h, const int* __restrict__ rowptr,
                          const int* __restrict__ csr_src, const float* __restrict__ dinv,
                          float* __restrict__ out) {
  __shared__ int sld[128];
  __shared__ float wld[128];
  int c = blockIdx.x, f = threadIdx.x;  // blockDim = 1<<LOGF
  float dc = dinv[c];
  int r0 = rowptr[c], r1 = rowptr[c + 1];
  float acc = bf2f(h[((size_t)c << LOGF) + f]) * dc;
  for (int base = r0; base < r1; base += 128) {
    int nb = min(128, r1 - base);
    if (f < nb) {
      int s = csr_src[base + f];
      sld[f] = s;
      wld[f] = dinv[s];
    }
    __syncthreads();
    for (int i = 0; i < nb; i++) acc += bf2f(h[((size_t)sld[i] << LOGF) + f]) * wld[i];
    __syncthreads();
  }
  out[((size_t)c << LOGF) + f] = acc * dc;
}

// SAGE: out = (sum_j x[src_j]) / max(deg,1); x strided (right half), out strided (left half)
__global__ void k_sage_agg(const unsigned short* __restrict__ x, const int* __restrict__ rowptr,
                           const int* __restrict__ csr_src, unsigned short* __restrict__ out) {
  __shared__ int sld[128];
  int c = blockIdx.x, f = threadIdx.x;  // 128
  int r0 = rowptr[c], r1 = rowptr[c + 1];
  float acc = 0.f;
  for (int base = r0; base < r1; base += 128) {
    int nb = min(128, r1 - base);
    if (f < nb) sld[f] = csr_src[base + f];
    __syncthreads();
    for (int i = 0; i < nb; i++) acc += bf2f(x[(size_t)sld[i] * 256 + f]);
    __syncthreads();
  }
  out[(size_t)c * 256 + f] = f2bf(acc / fmaxf((float)(r1 - r0), 1.f));
}

// Cheb: out[c] = -dinv0[c] * sum_j x[src_j]*dinv0[src_j]; x left half, out right half
__global__ void k_cheb_agg(const unsigned short* __restrict__ x, const int* __restrict__ rowptr,
                           const int* __restrict__ csr_src, const float* __restrict__ dinv0,
                           unsigned short* __restrict__ out) {
  __shared__ int sld[128];
  __shared__ float wld[128];
  int c = blockIdx.x, f = threadIdx.x;  // 128
  int r0 = rowptr[c], r1 = rowptr[c + 1];
  float acc = 0.f;
  for (int base = r0; base < r1; base += 128) {
    int nb = min(128, r1 - base);
    if (f < nb) {
      int s = csr_src[base + f];
      sld[f] = s;
      wld[f] = dinv0[s];
    }
    __syncthreads();
    for (int i = 0; i < nb; i++) acc += bf2f(x[(size_t)sld[i] * 256 + f]) * wld[i];
    __syncthreads();
  }
  out[(size_t)c * 256 + f] = f2bf(-acc * dinv0[c]);
}

// GAT: edge-softmax + weighted agg + self loop + bias + ELU -> bf16
__global__ void k_gat_agg(const unsigned short* __restrict__ h, const int* __restrict__ rowptr,
                          const int* __restrict__ csr_src, const float* __restrict__ a_s,
                          const float* __restrict__ a_d, const float* __restrict__ bias,
                          unsigned short* __restrict__ out) {
  __shared__ int sld[128];
  __shared__ float eld[128];
  int c = blockIdx.x, f = threadIdx.x;  // 128
  int r0 = rowptr[c], r1 = rowptr[c + 1];
  float adc = a_d[c];
  float es = a_s[c] + adc;
  es = es >= 0.f ? es : 0.2f * es;
  float m = es;
  for (int base = r0; base < r1; base += 128) {
    int nb = min(128, r1 - base);
    if (f < nb) {
      float v = a_s[csr_src[base + f]] + adc;
      eld[f] = v >= 0.f ? v : 0.2f * v;
    }
    __syncthreads();
    for (int i = 0; i < nb; i++) m = fmaxf(m, eld[i]);
    __syncthreads();
  }
  float den = expf(es - m);
  float acc = den * bf2f(h[((size_t)c << 7) + f]);
  for (int base = r0; base < r1; base += 128) {
    int nb = min(128, r1 - base);
    if (f < nb) {
      int s = csr_src[base + f];
      sld[f] = s;
      float v = a_s[s] + adc;
      v = v >= 0.f ? v : 0.2f * v;
      eld[f] = expf(v - m);
    }
    __syncthreads();
    for (int i = 0; i < nb; i++) {
      float w = eld[i];
      acc += w * bf2f(h[((size_t)sld[i] << 7) + f]);
      den += w;
    }
    __syncthreads();
  }
  float v = acc / den + bias[f];
  out[((size_t)c << 7) + f] = f2bf(v > 0.f ? v : expm1f(v));
}

// ---------------- batch norm (partials, no atomics) ----------------
__global__ void k_bn_stats(const float* __restrict__ x, float* __restrict__ psum,
                           float* __restrict__ psq, int F) {
  int tid = threadIdx.x;
  int f = tid & (F - 1);
  int rstep = 256 / F;
  int r0 = tid / F;
  int base = blockIdx.x * 64;  // grid 64
  float s = 0.f, s2 = 0.f;
  for (int rr = r0; rr < 64; rr += rstep) {
    float v = x[(size_t)(base + rr) * F + f];
    s += v;
    s2 += v * v;
  }
  int slot = blockIdx.x * rstep + r0;
  psum[(size_t)slot * F + f] = s;
  psq[(size_t)slot * F + f] = s2;
}

__global__ void k_bn_final(const float* __restrict__ psum, const float* __restrict__ psq,
                           const float* __restrict__ g, const float* __restrict__ be,
                           float* __restrict__ scale, float* __restrict__ shift, int F) {
  int f = threadIdx.x;  // F threads
  int S = 16384 / F;
  float s = 0.f, s2 = 0.f;
  for (int i = 0; i < S; i++) {
    s += psum[(size_t)i * F + f];
    s2 += psq[(size_t)i * F + f];
  }
  float invM = 1.f / (float)NN;
  float mu = s * invM;
  float var = s2 * invM - mu * mu;
  float sc = g[f] * rsqrtf(var + 1e-5f);
  scale[f] = sc;
  shift[f] = be[f] - mu * sc;
}

__global__ void k_bn_apply(const float* __restrict__ x, const float* __restrict__ scale,
                           const float* __restrict__ shift, unsigned short* __restrict__ y,
                           int ldY, int logF, int n) {
  int F1 = (1 << logF) - 1;
  for (int i = blockIdx.x * blockDim.x + threadIdx.x; i < n; i += gridDim.x * blockDim.x) {
    int row = i >> logF, f = i & F1;
    float v = fmaxf(x[i] * scale[f] + shift[f], 0.f);
    y[(size_t)row * ldY + f] = f2bf(v);
  }
}

// ---------------- GAT per-node dot products (bf16 h) ----------------
__global__ void k_gat_dots(const unsigned short* __restrict__ h, const float* __restrict__ asrc,
                           const float* __restrict__ adst, float* __restrict__ a_s,
                           float* __restrict__ a_d) {
  int n = blockIdx.x * 4 + (threadIdx.x >> 6), l = threadIdx.x & 63;  // 256 thr, 4 nodes
  float h0 = bf2f(h[n * 128 + l]), h1 = bf2f(h[n * 128 + 64 + l]);
  float hs = h0 * asrc[l] + h1 * asrc[64 + l];
  float hd = h0 * adst[l] + h1 * adst[64 + l];
  for (int off = 32; off; off >>= 1) {
    hs += __shfl_down(hs, off, 64);
    hd += __shfl_down(hd, off, 64);
  }
  if (l == 0) {
    a_s[n] = hs;
    a_d[n] = hd;
  }
}

// ---------------- launch ----------------
static inline int cdiv(int a, int b) { return (a + b - 1) / b; }

extern "C" void kernel_launch(void* const* d_in, const int* in_sizes, int n_in,
                              void* d_out, int out_size, void* d_ws, size_t ws_size,
                              hipStream_t stream) {
  const int* ei = (const int*)d_in[0];
  const int* ei0 = ei;
  const int* ei1 = ei + NE;
  const int* node_x = (const int*)d_in[1];
  const float* user_w = (const float*)d_in[2];
  const float* item_w = (const float*)d_in[3];
  const float* mlp_w1 = (const float*)d_in[4];
  const float* mlp_b1 = (const float*)d_in[5];
  const float* mlp_w2 = (const float*)d_in[6];
  const float* mlp_b2 = (const float*)d_in[7];
  const float* gcn_w1 = (const float*)d_in[8];
  // d_in[9] gcn_b1 / d_in[13] gcn_b2: cancelled by batch_norm mean subtraction
  const float* bn1_g = (const float*)d_in[10];
  const float* bn1_b = (const float*)d_in[11];
  const float* gcn_w2 = (const float*)d_in[12];
  const float* bn2_g = (const float*)d_in[14];
  const float* bn2_b = (const float*)d_in[15];
  const float* sage_wl = (const float*)d_in[16];
  const float* sage_bl = (const float*)d_in[17];
  const float* sage_wr = (const float*)d_in[18];
  const float* cheb_w0 = (const float*)d_in[19];
  const float* cheb_w1 = (const float*)d_in[20];
  const float* cheb_b = (const float*)d_in[21];
  const float* gat1_w = (const float*)d_in[22];
  const float* gat1_as = (const float*)d_in[23];
  const float* gat1_ad = (const float*)d_in[24];
  const float* gat1_b = (const float*)d_in[25];
  const float* gat2_w = (const float*)d_in[26];
  const float* gat2_as = (const float*)d_in[27];
  const float* gat2_ad = (const float*)d_in[28];
  const float* gat2_b = (const float*)d_in[29];
  const float* pred_w = (const float*)d_in[30];
  const float* pred_b = (const float*)d_in[31];

  // ---- workspace layout (~46 MB) ----
  char* w = (char*)d_ws;
  size_t off = 0;
  auto alloc = [&](size_t bytes) -> char* {
    char* p = w + off;
    off = (off + bytes + 255) & ~(size_t)255;
    return p;
  };
  unsigned short* x0b = (unsigned short*)alloc((size_t)NN * 128 * 2);
  unsigned short* x1b = (unsigned short*)alloc((size_t)NN * 1024 * 2);
  unsigned short* x2b = (unsigned short*)alloc((size_t)NN * 512 * 2);
  unsigned short* h1b = (unsigned short*)alloc((size_t)NN * 256 * 2);
  unsigned short* xab = (unsigned short*)alloc((size_t)NN * 256 * 2);
  unsigned short* catS = (unsigned short*)alloc((size_t)NN * 256 * 2);  // [sage_agg | xb]
  unsigned short* catC = (unsigned short*)alloc((size_t)NN * 256 * 2);  // [xa | cheb_agg]
  unsigned short* xb2 = (unsigned short*)alloc((size_t)NN * 128 * 2);
  unsigned short* hb = (unsigned short*)alloc((size_t)NN * 128 * 2);
  unsigned short* xa2 = (unsigned short*)alloc((size_t)NN * 128 * 2);
  unsigned short* xb3 = (unsigned short*)alloc((size_t)NN * 128 * 2);
  float* agg = (float*)alloc((size_t)NN * 256 * 4);
  unsigned short* w1t = (unsigned short*)alloc((size_t)1024 * 128 * 2);
  unsigned short* w2t = (unsigned short*)alloc((size_t)512 * 1024 * 2);
  unsigned short* g1t = (unsigned short*)alloc((size_t)256 * 512 * 2);
  unsigned short* g2t = (unsigned short*)alloc((size_t)128 * 256 * 2);
  unsigned short* sgt = (unsigned short*)alloc((size_t)128 * 256 * 2);  // [Wl;Wr]^T
  unsigned short* cht = (unsigned short*)alloc((size_t)128 * 256 * 2);  // [W0;W1]^T
  unsigned short* a1t = (unsigned short*)alloc((size_t)128 * 128 * 2);
  unsigned short* a2t = (unsigned short*)alloc((size_t)128 * 128 * 2);
  unsigned short* predT = (unsigned short*)alloc((size_t)NPAD * 128 * 2);
  int* deg0 = (int*)alloc(NN * 4);
  int* deg1 = (int*)alloc(NN * 4);  // contiguous after deg0
  int* rowptr = (int*)alloc((NN + 1) * 4);
  int* cursor = (int*)alloc(NN * 4);
  int* csr_src = (int*)alloc(NE * 4);
  float* dinvA = (float*)alloc(NN * 4);
  float* dinv0 = (float*)alloc(NN * 4);
  float* a_s = (float*)alloc(NN * 4);
  float* a_d = (float*)alloc(NN * 4);
  float* psum = (float*)alloc(16384 * 4);
  float* psq = (float*)alloc(16384 * 4);
  float* bscale = (float*)alloc(256 * 4);
  float* bshift = (float*)alloc(256 * 4);

  // ---- weight conversion (one launch) ----
  CvtArgs ca;
  int t0 = 0;
  auto mkd = [&](int i, const float* src, unsigned short* dst, int K, int N, int ld, int koff,
                 int ntx) {
    ca.d[i] = {src, dst, K, N, ld, koff, t0, ntx};
    t0 += ntx * (K / 32);
  };
  mkd(0, mlp_w1, w1t, 128, 1024, 128, 0, 32);
  mkd(1, mlp_w2, w2t, 1024, 512, 1024, 0, 16);
  mkd(2, gcn_w1, g1t, 512, 256, 512, 0, 8);
  mkd(3, gcn_w2, g2t, 256, 128, 256, 0, 4);
  mkd(4, sage_wl, sgt, 128, 128, 256, 0, 4);
  mkd(5, sage_wr, sgt, 128, 128, 256, 128, 4);
  mkd(6, cheb_w0, cht, 128, 128, 256, 0, 4);
  mkd(7, cheb_w1, cht, 128, 128, 256, 128, 4);
  mkd(8, gat1_w, a1t, 128, 128, 128, 0, 4);
  mkd(9, gat2_w, a2t, 128, 128, 128, 0, 4);
  mkd(10, pred_w, predT, 128, NCLS, 128, 0, NPAD / 32);
  k_cvt_all<<<t0, 256, 0, stream>>>(ca);

  // ---- CSR build ----
  hipMemsetAsync(deg0, 0, 2 * NN * 4, stream);  // deg0+deg1 contiguous
  k_count2<<<512, 256, 0, stream>>>(ei, deg0, deg1);
  k_scan4096<<<1, 1024, 0, stream>>>(deg1, rowptr, cursor, dinvA);
  k_fill<<<cdiv(NE, 256), 256, 0, stream>>>(ei0, ei1, cursor, csr_src);
  k_dinv<<<cdiv(NN, 256), 256, 0, stream>>>(deg0, dinv0, NN, 0);

  // ---- trunk ----
  k_gather<<<NN, 128, 0, stream>>>(node_x, user_w, item_w, x0b);
  k_bgemm<1><<<dim3(8, 32), 256, 0, stream>>>(x0b, w1t, mlp_b1, x1b, 1024, 128, 1);
  k_bgemm<1><<<dim3(4, 32), 256, 0, stream>>>(x1b, w2t, mlp_b2, x2b, 512, 1024, 1);

  // GCN1 (512 -> 256)
  k_bgemm_s<<<dim3(2, 128), 256, 0, stream>>>(x2b, g1t, nullptr, h1b, 256, 512, 0);
  k_gcn_agg<8><<<NN, 256, 0, stream>>>(h1b, rowptr, csr_src, dinvA, agg);
  k_bn_stats<<<64, 256, 0, stream>>>(agg, psum, psq, 256);
  k_bn_final<<<1, 256, 0, stream>>>(psum, psq, bn1_g, bn1_b, bscale, bshift, 256);
  k_bn_apply<<<1024, 256, 0, stream>>>(agg, bscale, bshift, xab, 256, 8, NN * 256);

  // GCN2 (256 -> 128); BN output goes into catS right half
  k_bgemm_s<<<dim3(1, 128), 256, 0, stream>>>(xab, g2t, nullptr, hb, 128, 256, 0);
  k_gcn_agg<7><<<NN, 128, 0, stream>>>(hb, rowptr, csr_src, dinvA, agg);
  k_bn_stats<<<64, 256, 0, stream>>>(agg, psum, psq, 128);
  k_bn_final<<<1, 128, 0, stream>>>(psum, psq, bn2_g, bn2_b, bscale, bshift, 128);
  k_bn_apply<<<1024, 256, 0, stream>>>(agg, bscale, bshift, catS + 128, 256, 7, NN * 128);

  // SAGE: agg into catS left; fused GEMM [agg|x] @ [Wl;Wr] + bl, relu -> catC left
  k_sage_agg<<<NN, 128, 0, stream>>>(catS + 128, rowptr, csr_src, catS);
  k_bgemm_s<<<dim3(1, 128), 256, 0, stream>>>(catS, sgt, sage_bl, catC, 256, 256, 1);

  // Cheb: agg into catC right; fused GEMM [x|tx1] @ [W0;W1] + b, relu -> xb2
  k_cheb_agg<<<NN, 128, 0, stream>>>(catC, rowptr, csr_src, dinv0, catC + 128);
  k_bgemm_s<<<dim3(1, 128), 256, 0, stream>>>(catC, cht, cheb_b, xb2, 128, 256, 1);

  // GAT1
  k_bgemm_s<<<dim3(1, 128), 256, 0, stream>>>(xb2, a1t, nullptr, hb, 128, 128, 0);
  k_gat_dots<<<NN / 4, 256, 0, stream>>>(hb, gat1_as, gat1_ad, a_s, a_d);
  k_gat_agg<<<NN, 128, 0, stream>>>(hb, rowptr, csr_src, a_s, a_d, gat1_b, xa2);

  // GAT2
  k_bgemm_s<<<dim3(1, 128), 256, 0, stream>>>(xa2, a2t, nullptr, hb, 128, 128, 0);
  k_gat_dots<<<NN / 4, 256, 0, stream>>>(hb, gat2_as, gat2_ad, a_s, a_d);
  k_gat_agg<<<NN, 128, 0, stream>>>(hb, rowptr, csr_src, a_s, a_d, gat2_b, xb3);

  // ---- final prediction GEMM ----
  k_bgemm<0><<<dim3(NPAD / 128, 32), 256, 0, stream>>>(xb3, predT, pred_b, (float*)d_out, NCLS, 128, 0);
}